// Round 6
// baseline (748.848 us; speedup 1.0000x reference)
//
#include <hip/hip_runtime.h>
#include <hip/hip_bf16.h>
#include <math.h>

#define NTOK 65536
#define C 180
#define KP1 192      // padded K for C=180
#define RCHUNK 32768 // rows per chunk (128 windows) for the MLP fallback
#define LOG2E 1.4426950408889634f

typedef __attribute__((ext_vector_type(8))) __bf16 bf16x8;
typedef __attribute__((ext_vector_type(4))) float floatx4;

__device__ __forceinline__ float gelu_f(float v) {
    return 0.5f * v * (1.f + erff(v * 0.7071067811865475f));
}
__device__ __forceinline__ float bflo(unsigned int u) { return __uint_as_float(u << 16); }
__device__ __forceinline__ float bfhi(unsigned int u) { return __uint_as_float(u & 0xffff0000u); }

// window-row (shifted-window order) -> pixel row index in [0, 65536)
__device__ __forceinline__ int win2pix(int wrow) {
    int wi = wrow >> 8, ni = wrow & 255;
    int r2 = ((wi >> 4) << 4) | (ni >> 4);
    int c2 = ((wi & 15) << 4) | (ni & 15);
    int r = (r2 + 8) & 255, c = (c2 + 8) & 255;
    return (r << 8) | c;
}

// ---------------- LayerNorm: fp32 in (stride 180) -> bf16 out (stride 192, zero pad) -----------
__global__ __launch_bounds__(256) void ln_k(const float* __restrict__ x,
                                            const float* __restrict__ g,
                                            const float* __restrict__ b,
                                            __hip_bfloat16* __restrict__ y) {
    const int wav = threadIdx.x >> 6;
    const int lane = threadIdx.x & 63;
    const int row = blockIdx.x * 4 + wav;
    const float* xr = x + (size_t)row * C;
    float v0 = xr[lane];
    float v1 = xr[lane + 64];
    float v2 = (lane < C - 128) ? xr[lane + 128] : 0.f;
    float sum = v0 + v1 + v2;
    float sq = v0 * v0 + v1 * v1 + v2 * v2;
#pragma unroll
    for (int off = 32; off >= 1; off >>= 1) {
        sum += __shfl_xor(sum, off, 64);
        sq += __shfl_xor(sq, off, 64);
    }
    const float mu = sum * (1.f / C);
    const float var = sq * (1.f / C) - mu * mu;
    const float rstd = rsqrtf(var + 1e-5f);
    __hip_bfloat16* yr = y + (size_t)row * KP1;
#pragma unroll
    for (int e = 0; e < 3; ++e) {
        int col = lane + 64 * e;
        float val = 0.f;
        if (col < C) {
            float vv = (e == 0) ? v0 : (e == 1 ? v1 : v2);
            val = (vv - mu) * rstd * g[col] + b[col];
        }
        yr[col] = __float2bfloat16(val);
    }
}

// ---------------- fused weight/bias prep (one dispatch) ----------------
__device__ __forceinline__ void wconv_item(const float* __restrict__ w,
                                           __hip_bfloat16* __restrict__ wb,
                                           int O, int I, int OCP, int KP, int idx) {
    int tap = idx / (OCP * KP);
    int rem = idx - tap * (OCP * KP);
    int oc = rem / KP, ch = rem - oc * KP;
    float v = (oc < O && ch < I) ? w[((size_t)(oc * I + ch)) * 9 + tap] : 0.f;
    wb[idx] = __float2bfloat16(v);
}
__device__ __forceinline__ void wprep_item(const float* __restrict__ w,
                                           __hip_bfloat16* __restrict__ bt,
                                           int K, int N, int KPd, int idx) {
    int n = idx / KPd, k = idx - n * KPd;
    float v = (n < N && k < K) ? w[(size_t)k * N + n] : 0.f;
    bt[idx] = __float2bfloat16(v);
}
// ranges: [0,65536) rpbM (4 types x 6 heads fused rpb+mask, pre-scaled by log2e for exp2) |
//         +110592 wconv1 | +110592 wconv2 | +122880 qkv | +36864 proj | +147456 f1 |
//         +147456 f2   total 741,376
__global__ void prep_all_k(const int* __restrict__ rpi, const float* __restrict__ table,
                           const float* __restrict__ mask,
                           __hip_bfloat16* __restrict__ rpbM,
                           const float* __restrict__ c1w, __hip_bfloat16* __restrict__ wb1,
                           const float* __restrict__ c2w, __hip_bfloat16* __restrict__ wb2,
                           const float* __restrict__ qkvw, __hip_bfloat16* __restrict__ qkvbt,
                           const float* __restrict__ projw, __hip_bfloat16* __restrict__ projbt,
                           const float* __restrict__ f1w, __hip_bfloat16* __restrict__ f1bt,
                           const float* __restrict__ f2w, __hip_bfloat16* __restrict__ f2bt) {
    int idx = blockIdx.x * 256 + threadIdx.x;
    if (idx < 65536) {
        int t = rpi[idx];
        // 4 distinct shifted-window mask patterns: interior / right col / bottom row / corner.
        float m1 = mask[(size_t)15 * 65536 + idx];
        float m2 = mask[(size_t)240 * 65536 + idx];
        float m3 = mask[(size_t)255 * 65536 + idx];
#pragma unroll
        for (int h = 0; h < 6; ++h) {
            float base = table[t * 6 + h];
            rpbM[((size_t)(0 * 6 + h)) * 65536 + idx] = __float2bfloat16(base * LOG2E);
            rpbM[((size_t)(1 * 6 + h)) * 65536 + idx] = __float2bfloat16((base + m1) * LOG2E);
            rpbM[((size_t)(2 * 6 + h)) * 65536 + idx] = __float2bfloat16((base + m2) * LOG2E);
            rpbM[((size_t)(3 * 6 + h)) * 65536 + idx] = __float2bfloat16((base + m3) * LOG2E);
        }
        return;
    }
    idx -= 65536;
    if (idx < 110592) { wconv_item(c1w, wb1, 60, 180, 64, 192, idx); return; }
    idx -= 110592;
    if (idx < 110592) { wconv_item(c2w, wb2, 180, 60, 192, 64, idx); return; }
    idx -= 110592;
    if (idx < 122880) { wprep_item(qkvw, qkvbt, 180, 540, 192, idx); return; }
    idx -= 122880;
    if (idx < 36864) { wprep_item(projw, projbt, 180, 180, 192, idx); return; }
    idx -= 36864;
    if (idx < 147456) { wprep_item(f1w, f1bt, 180, 720, 192, idx); return; }
    idx -= 147456;
    if (idx < 147456) { wprep_item(f2w, f2bt, 720, 180, 768, idx); return; }
}

// ---------------- MFMA implicit-GEMM conv 3x3, NHWC bf16 in, pad 1 ----------------
template <int TH, int CINP, int COUT, int OSTR, int ACT, int OUTBF>
__global__ __launch_bounds__(256) void mconv_k(const __hip_bfloat16* __restrict__ in, int istr,
                                               const __hip_bfloat16* __restrict__ wb,
                                               const float* __restrict__ bias,
                                               void* __restrict__ outp) {
    constexpr int MI = TH / 4;
    __shared__ __hip_bfloat16 sP[(TH + 2) * 18 * 40];
    __shared__ __hip_bfloat16 sW[9 * 64 * 40];
    const int tid = threadIdx.x;
    const int tr0 = (blockIdx.x >> 4) * TH, tc0 = (blockIdx.x & 15) * 16;
    const int ocbase = blockIdx.y * 64;
    const int w = tid >> 6, lane = tid & 63, fr = lane & 15, q = lane >> 4;
    constexpr int OCP = ((COUT + 63) / 64) * 64;
    floatx4 acc[MI][4] = {};
    for (int c0 = 0; c0 < CINP; c0 += 32) {
        for (int l = tid; l < (TH + 2) * 18 * 4; l += 256) {
            int pos = l >> 2, part = l & 3;
            int pr = pos / 18, pc = pos - pr * 18;
            int gr = tr0 + pr - 1, gc = tc0 + pc - 1;
            float4 v = make_float4(0.f, 0.f, 0.f, 0.f);
            if (gr >= 0 && gr < 256 && gc >= 0 && gc < 256)
                v = *(const float4*)(in + (size_t)(gr * 256 + gc) * istr + c0 + part * 8);
            *(float4*)(sP + pos * 40 + part * 8) = v;
        }
        for (int l = tid; l < 9 * 64 * 4; l += 256) {
            int part = l & 3, oc = (l >> 2) & 63, tap = l >> 8;
            *(float4*)(sW + tap * 2560 + oc * 40 + part * 8) =
                *(const float4*)(wb + (size_t)(tap * OCP + ocbase + oc) * CINP + c0 + part * 8);
        }
        __syncthreads();
#pragma unroll
        for (int tap = 0; tap < 9; ++tap) {
            const int dy = tap / 3, dx = tap - 3 * (tap / 3);
            bf16x8 af[MI], bw[4];
#pragma unroll
            for (int mi = 0; mi < MI; ++mi) {
                int pr = MI * w + mi + dy, pc = fr + dx;
                af[mi] = *(const bf16x8*)(sP + (pr * 18 + pc) * 40 + q * 8);
            }
#pragma unroll
            for (int nj = 0; nj < 4; ++nj)
                bw[nj] = *(const bf16x8*)(sW + tap * 2560 + (nj * 16 + fr) * 40 + q * 8);
#pragma unroll
            for (int mi = 0; mi < MI; ++mi)
#pragma unroll
                for (int nj = 0; nj < 4; ++nj)
                    acc[mi][nj] =
                        __builtin_amdgcn_mfma_f32_16x16x32_bf16(af[mi], bw[nj], acc[mi][nj], 0, 0, 0);
        }
        __syncthreads();
    }
#pragma unroll
    for (int mi = 0; mi < MI; ++mi) {
#pragma unroll
        for (int r = 0; r < 4; ++r) {
            const int irow = tr0 + MI * w + mi;
            const int icol = tc0 + q * 4 + r;
            const size_t obase = (size_t)(irow * 256 + icol) * OSTR + ocbase;
#pragma unroll
            for (int nj = 0; nj < 4; ++nj) {
                int oc = ocbase + nj * 16 + fr;
                float bv = (oc < COUT) ? bias[oc] : 0.f;
                float v = acc[mi][nj][r] + bv;
                if (ACT) v = gelu_f(v);
                if (OUTBF) {
                    ((__hip_bfloat16*)outp)[obase + nj * 16 + fr] = __float2bfloat16(v);
                } else {
                    if (oc < COUT) ((float*)outp)[obase + nj * 16 + fr] = v;
                }
            }
        }
    }
}

// ---------------- channel sums ----------------
__global__ __launch_bounds__(192) void chansum_k(const float* __restrict__ y2,
                                                 float* __restrict__ partials) {
    const int tid = threadIdx.x;
    if (tid >= C) return;
    const size_t base = (size_t)blockIdx.x * 256 * C;
    float s = 0.f;
    for (int p = 0; p < 256; ++p) s += y2[base + (size_t)p * C + tid];
    partials[blockIdx.x * C + tid] = s;
}

// ---------------- channel attention MLP (1 block) ----------------
__global__ __launch_bounds__(256) void ca_k(const float* __restrict__ partials,
                                            const float* __restrict__ w1, const float* __restrict__ b1,
                                            const float* __restrict__ w2, const float* __restrict__ b2,
                                            float* __restrict__ scale) {
    __shared__ float mean[C];
    __shared__ float s1[6];
    const int tid = threadIdx.x;
    if (tid < C) {
        float s = 0.f;
        for (int b_ = 0; b_ < 256; ++b_) s += partials[b_ * C + tid];
        mean[tid] = s * (1.f / 65536.f);
    }
    __syncthreads();
    if (tid < 6) {
        float s = b1[tid];
        for (int ch = 0; ch < C; ++ch) s += mean[ch] * w1[tid * C + ch];
        s1[tid] = fmaxf(s, 0.f);
    }
    __syncthreads();
    if (tid < C) {
        float s = b2[tid];
#pragma unroll
        for (int j = 0; j < 6; ++j) s += s1[j] * w2[tid * 6 + j];
        scale[tid] = 1.f / (1.f + __expf(-s));
    }
}

// ---------------- bf16 MFMA GEMM: BM=128, BN in {64,128}, BK=32, 4 waves (2x2) ----------
// Grid is (M-blocks, N-blocks): m0 from blockIdx.x so linear_bid%8 == blockIdx.x%8 -> each
// XCD keeps a stable A working set across all N-passes (A re-reads become L2 hits).
// Plain stores: outputs feed the NEXT dispatch (round-4 lesson: nt stores cost +128 us).
template <int MODE, int BN>
__global__ __launch_bounds__(256) void mgemm_k(const unsigned short* __restrict__ A,
                                               const unsigned short* __restrict__ BT,
                                               const float* __restrict__ bias,
                                               const float* __restrict__ xres,
                                               const float* __restrict__ scale,
                                               void* __restrict__ Cout,
                                               int KPd, int N, int cstride, int rowoff) {
    __shared__ unsigned short As[128 * 40];
    __shared__ unsigned short Bs[BN * 40];
    constexpr int NJ = BN / 32;
    const int tid = threadIdx.x;
    const int m0 = blockIdx.x * 128, n0 = blockIdx.y * BN;
    const int arow_l = tid >> 1;
    const int akofs = (tid & 1) * 16;
    size_t arow;
    if (MODE == 3)
        arow = (size_t)win2pix(rowoff + m0 + arow_l) * KPd;
    else
        arow = (size_t)(m0 + arow_l) * KPd;
    const int brow_l = (BN == 128) ? (tid >> 1) : (tid >> 2);
    const int bkofs = (BN == 128) ? ((tid & 1) * 16) : ((tid & 3) * 8);
    const size_t brow = (size_t)(n0 + brow_l) * KPd;
    const int wave = tid >> 6, lane = tid & 63;
    const int wm = (wave & 1) * 64, wn = (wave >> 1) * (BN / 2);
    const int fr = lane & 15, q = lane >> 4;
    floatx4 acc[4][NJ] = {};
    for (int k0 = 0; k0 < KPd; k0 += 32) {
        if (MODE == 5) {
            const unsigned short* Ap = A + ((size_t)(k0 >> 5) * cstride + (m0 + arow_l)) * 32;
            *(float4*)(&As[arow_l * 40 + akofs]) = *(const float4*)(Ap + akofs);
            *(float4*)(&As[arow_l * 40 + akofs + 8]) = *(const float4*)(Ap + akofs + 8);
        } else {
            *(float4*)(&As[arow_l * 40 + akofs]) = *(const float4*)(A + arow + k0 + akofs);
            *(float4*)(&As[arow_l * 40 + akofs + 8]) = *(const float4*)(A + arow + k0 + akofs + 8);
        }
        if (BN == 128) {
            *(float4*)(&Bs[brow_l * 40 + bkofs]) = *(const float4*)(BT + brow + k0 + bkofs);
            *(float4*)(&Bs[brow_l * 40 + bkofs + 8]) = *(const float4*)(BT + brow + k0 + bkofs + 8);
        } else {
            *(float4*)(&Bs[brow_l * 40 + bkofs]) = *(const float4*)(BT + brow + k0 + bkofs);
        }
        __syncthreads();
        bf16x8 af[4], fB[NJ];
#pragma unroll
        for (int i = 0; i < 4; ++i)
            af[i] = *(const bf16x8*)(&As[(wm + i * 16 + fr) * 40 + q * 8]);
#pragma unroll
        for (int j = 0; j < NJ; ++j)
            fB[j] = *(const bf16x8*)(&Bs[(wn + j * 16 + fr) * 40 + q * 8]);
#pragma unroll
        for (int i = 0; i < 4; ++i)
#pragma unroll
            for (int j = 0; j < NJ; ++j)
                acc[i][j] = __builtin_amdgcn_mfma_f32_16x16x32_bf16(af[i], fB[j], acc[i][j], 0, 0, 0);
        __syncthreads();
    }
#pragma unroll
    for (int i = 0; i < 4; ++i) {
#pragma unroll
        for (int r = 0; r < 4; ++r) {
            const int grow = m0 + wm + i * 16 + q * 4 + r;
            int pix = 0;
            if (MODE == 5) pix = win2pix(rowoff + grow);
#pragma unroll
            for (int j = 0; j < NJ; ++j) {
                const int col = n0 + wn + j * 16 + fr;
                float v = acc[i][j][r];
                if (MODE == 1 || MODE == 3) {
                    if (col < cstride) {
                        float vv = 0.f;
                        if (col < N) {
                            vv = v + bias[col];
                            if (MODE == 1) vv = gelu_f(vv);
                        }
                        ((__hip_bfloat16*)Cout)[(size_t)grow * cstride + col] = __float2bfloat16(vv);
                    }
                } else if (MODE == 2) {
                    if (col < N) {
                        float* o = (float*)Cout;
                        size_t ix = (size_t)grow * 180 + col;
                        o[ix] = v + bias[col] + xres[ix];
                    }
                } else if (MODE == 5) {
                    if (col < N) {
                        float* o = (float*)Cout;
                        size_t ix = (size_t)pix * 180 + col;
                        o[ix] = xres[ix] + v + bias[col] + o[ix] * scale[col] * 0.01f;
                    }
                }
            }
        }
    }
}

// ---------------- MFMA flash attention v10 ----------------
// = v9 + rb double-buffer across nc (v8's structure, but WITHOUT the (256,5) bound that
// caused v8's spill: under (256,4) the allocator has room to 128 VGPR, expected ~96-100,
// which keeps 5 waves/SIMD and the LDS-limited 5 blocks/CU). + exp2 path (rpbM pre-scaled
// by log2e at prep; saves the v_mul hidden in __expf).
__global__ __launch_bounds__(256, 4) void attn10_k(const __hip_bfloat16* __restrict__ qkv,  // [R][576]
                                                   const __hip_bfloat16* __restrict__ rpbM, // [typ][h][qry][key]
                                                   __hip_bfloat16* __restrict__ attn_out,   // [6][rows][32]
                                                   int wbase, int rows) {
    const int wl = blockIdx.x, h = blockIdx.y;
    const int wig = wbase + wl;
    const int typ = (((wig >> 4) == 15) ? 2 : 0) + (((wig & 15) == 15) ? 1 : 0);
    const int tid = threadIdx.x;
    const int w = tid >> 6, lane = tid & 63;
    const int fr = lane & 15, q = lane >> 4;
    // kk: logical [key][d0..31], byte = key*64 + ((slot ^ (key&3))<<4) + inslot, slot=d>>3
    // vT: logical [d][key0..255], byte = d*512 + (((key>>3) ^ d)<<4) + (key&7)*2
    __shared__ __hip_bfloat16 kk[256 * 32];
    __shared__ __hip_bfloat16 vT[32 * 256];

    union UB2 { unsigned int u; __hip_bfloat162 h2; };
    union U8 { unsigned int u[4]; bf16x8 v; };

    // ---- Q fragments (global, independent of LDS) ----
    const int rowbase = wl * 256 + w * 64;
    bf16x8 qf[4];
#pragma unroll
    for (int qi = 0; qi < 4; ++qi) {
        const unsigned int* p32 =
            (const unsigned int*)(qkv + (size_t)(rowbase + qi * 16 + fr) * 576 + h * 30);
        U8 t;
#pragma unroll
        for (int jj = 0; jj < 4; ++jj) t.u[jj] = p32[q * 4 + jj];
        qf[qi] = t.v;
    }

    // ---- rb prefetch for nc=0: issue before staging so L2 latency hides under the drain ----
    const __hip_bfloat16* rpbh = rpbM + ((size_t)(typ * 6 + h)) * 65536;
    uint2 rb[2][4][4];
#pragma unroll
    for (int qi = 0; qi < 4; ++qi) {
        const size_t qoff = ((size_t)(w * 64 + qi * 16 + fr)) * 256 + q * 4;
#pragma unroll
        for (int ki = 0; ki < 4; ++ki)
            rb[0][qi][ki] = *(const uint2*)(rpbh + qoff + ki * 16);
    }

    // ---- K/V staging into swizzled LDS ----
    for (int l = tid; l < 256 * 15; l += 256) {
        int key = l / 15, dw_ = l - key * 15;
        const unsigned int* ks =
            (const unsigned int*)(qkv + (size_t)(wl * 256 + key) * 576 + 180 + h * 30);
        unsigned int kv = ks[dw_];
        *(unsigned int*)((char*)kk + key * 64 + (((dw_ >> 2) ^ (key & 3)) << 4) + ((dw_ & 3) << 2)) = kv;
        UB2 vv; vv.u = ks[90 + dw_];
        const int d0 = 2 * dw_, d1 = d0 + 1;
        *(__hip_bfloat16*)((char*)vT + d0 * 512 + (((key >> 3) ^ d0) << 4) + ((key & 7) << 1)) = vv.h2.x;
        *(__hip_bfloat16*)((char*)vT + d1 * 512 + (((key >> 3) ^ d1) << 4) + ((key & 7) << 1)) = vv.h2.y;
    }
    // zero pads: kk d=30,31 (dword 15 of each key row); vT d=30,31 all keys
    *(unsigned int*)((char*)kk + tid * 64 + ((3 ^ (tid & 3)) << 4) + 12) = 0u;
    for (int l = tid; l < 2 * 256; l += 256) {
        int d = 30 + (l >> 8), key = l & 255;
        *(__hip_bfloat16*)((char*)vT + d * 512 + (((key >> 3) ^ d) << 4) + ((key & 7) << 1)) =
            __float2bfloat16(0.f);
    }
    __syncthreads();

    const float SC2 = 0.26339891239045137f;  // (1/sqrt(30)) * log2(e)
    float lsum[4] = {};
    floatx4 o_[4][2] = {};
    const int srcA = fr + ((q & 1) << 5);
    const int srcB = srcA + 16;

#pragma unroll
    for (int nc = 0; nc < 4; ++nc) {
        const int cur = nc & 1;
        // prefetch next nc's bias block (consumed one iteration later)
        if (nc < 3) {
#pragma unroll
            for (int qi = 0; qi < 4; ++qi) {
                const size_t qoff =
                    ((size_t)(w * 64 + qi * 16 + fr)) * 256 + (nc + 1) * 64 + q * 4;
#pragma unroll
                for (int ki = 0; ki < 4; ++ki)
                    rb[cur ^ 1][qi][ki] = *(const uint2*)(rpbh + qoff + ki * 16);
            }
        }
        bf16x8 kf[4];
#pragma unroll
        for (int ki = 0; ki < 4; ++ki) {
            const int key = nc * 64 + ki * 16 + fr;
            kf[ki] = *(const bf16x8*)((const char*)kk + key * 64 + ((q ^ (fr & 3)) << 4));
        }
        unsigned int dw[4][4][2];
#pragma unroll
        for (int qi = 0; qi < 4; ++qi) {
            floatx4 s_[4] = {};
#pragma unroll
            for (int ki = 0; ki < 4; ++ki)
                s_[ki] = __builtin_amdgcn_mfma_f32_16x16x32_bf16(kf[ki], qf[qi], s_[ki], 0, 0, 0);
#pragma unroll
            for (int ki = 0; ki < 4; ++ki) {
                uint2 rbv = rb[cur][qi][ki];
                float b0 = bflo(rbv.x), b1 = bfhi(rbv.x), b2 = bflo(rbv.y), b3 = bfhi(rbv.y);
                float p0 = exp2f(fmaf(s_[ki][0], SC2, b0));
                float p1 = exp2f(fmaf(s_[ki][1], SC2, b1));
                float p2 = exp2f(fmaf(s_[ki][2], SC2, b2));
                float p3 = exp2f(fmaf(s_[ki][3], SC2, b3));
                lsum[qi] += (p0 + p1) + (p2 + p3);
                __hip_bfloat162 lo = {__float2bfloat16(p0), __float2bfloat16(p1)};
                __hip_bfloat162 hi = {__float2bfloat16(p2), __float2bfloat16(p3)};
                UB2 ul, uh; ul.h2 = lo; uh.h2 = hi;
                dw[ki][qi][0] = ul.u;
                dw[ki][qi][1] = uh.u;
            }
        }
#pragma unroll
        for (int kc = 0; kc < 2; ++kc) {
            bf16x8 pa[4];
#pragma unroll
            for (int mi = 0; mi < 4; ++mi) {
                unsigned g0 = __shfl((int)dw[2 * kc][mi][0], srcA, 64);
                unsigned g1 = __shfl((int)dw[2 * kc][mi][1], srcA, 64);
                unsigned g2 = __shfl((int)dw[2 * kc][mi][0], srcB, 64);
                unsigned g3 = __shfl((int)dw[2 * kc][mi][1], srcB, 64);
                unsigned h0 = __shfl((int)dw[2 * kc + 1][mi][0], srcA, 64);
                unsigned h1 = __shfl((int)dw[2 * kc + 1][mi][1], srcA, 64);
                unsigned h2 = __shfl((int)dw[2 * kc + 1][mi][0], srcB, 64);
                unsigned h3 = __shfl((int)dw[2 * kc + 1][mi][1], srcB, 64);
                U8 t;
                const bool lo = (q < 2);
                t.u[0] = lo ? g0 : h0;
                t.u[1] = lo ? g1 : h1;
                t.u[2] = lo ? g2 : h2;
                t.u[3] = lo ? g3 : h3;
                pa[mi] = t.v;
            }
            bf16x8 vb[2];
#pragma unroll
            for (int dj = 0; dj < 2; ++dj) {
                const int d = dj * 16 + fr;
                vb[dj] = *(const bf16x8*)((const char*)vT + d * 512 +
                                          (((nc * 8 + kc * 4 + q) ^ d) << 4));
            }
#pragma unroll
            for (int mi = 0; mi < 4; ++mi)
#pragma unroll
                for (int dj = 0; dj < 2; ++dj)
                    o_[mi][dj] =
                        __builtin_amdgcn_mfma_f32_16x16x32_bf16(pa[mi], vb[dj], o_[mi][dj], 0, 0, 0);
        }
    }
    // row sums: reduce across q-groups, redistribute via shfl
#pragma unroll
    for (int qi = 0; qi < 4; ++qi) {
        lsum[qi] += __shfl_xor(lsum[qi], 16, 64);
        lsum[qi] += __shfl_xor(lsum[qi], 32, 64);
    }
    __hip_bfloat16* plane = attn_out + (size_t)h * rows * 32;
#pragma unroll
    for (int mi = 0; mi < 4; ++mi) {
#pragma unroll
        for (int r = 0; r < 4; ++r) {
            float tot = __shfl(lsum[mi], q * 4 + r, 64);
            float inv = 1.f / tot;
            const int row_local = rowbase + mi * 16 + q * 4 + r;
            __hip_bfloat16* orow = plane + (size_t)row_local * 32;
#pragma unroll
            for (int dj = 0; dj < 2; ++dj) {
                int d = dj * 16 + fr;
                float val = (d < 30) ? o_[mi][dj][r] * inv : 0.f;
                orow[d] = __float2bfloat16(val);
            }
        }
    }
}

extern "C" void kernel_launch(void* const* d_in, const int* in_sizes, int n_in, void* d_out,
                              int out_size, void* d_ws, size_t ws_size, hipStream_t stream) {
    (void)in_sizes; (void)n_in; (void)out_size;
    const float* x = (const float*)d_in[0];
    const int* rpi = (const int*)d_in[3];
    const float* mask = (const float*)d_in[4];
    const float* n1g = (const float*)d_in[5];
    const float* n1b = (const float*)d_in[6];
    const float* qkvw = (const float*)d_in[7];
    const float* qkvb = (const float*)d_in[8];
    const float* rpbt = (const float*)d_in[9];
    const float* projw = (const float*)d_in[10];
    const float* projb = (const float*)d_in[11];
    const float* c1w = (const float*)d_in[12];
    const float* c1b = (const float*)d_in[13];
    const float* c2w = (const float*)d_in[14];
    const float* c2b = (const float*)d_in[15];
    const float* ca1w = (const float*)d_in[16];
    const float* ca1b = (const float*)d_in[17];
    const float* ca2w = (const float*)d_in[18];
    const float* ca2b = (const float*)d_in[19];
    const float* n2g = (const float*)d_in[20];
    const float* n2b = (const float*)d_in[21];
    const float* f1w = (const float*)d_in[22];
    const float* f1b = (const float*)d_in[23];
    const float* f2w = (const float*)d_in[24];
    const float* f2b = (const float*)d_in[25];

    float* ws = (float*)d_ws;
    float* out = (float*)d_out;  // y2 -> x2 -> final output (in place, disjoint phases)

    // Merged attention path needs 130,511,616 B of workspace; fall back to 2-chunk if smaller.
    const int merged = (ws_size >= 130511616ull) ? 1 : 0;
    const int RATT = merged ? 65536 : 32768;
    const int nck = merged ? 1 : 2;
    const size_t bufCf = merged ? 25165824u : 12582912u;   // floats in the big shared region
    const size_t attnCoff = merged ? 18874368u : 9437184u; // float offset of attnC inside bufC

    // workspace layout (floats; offsets 16B-aligned)
    float* xn_f     = ws;                    // 6,291,456 (65536x192 bf16)
    float* bufC     = xn_f + 6291456;        // y1b | qkvC+attnC | h1 (all bf16)
    float* partials = bufC + bufCf;          // 46,080
    float* scalep   = partials + 46080;      // 192
    float* rpbM_f   = scalep + 192;          // 786,432 (4x6x65536 bf16, rpb+mask fused)
    float* wb1_f    = rpbM_f + 786432;       // 55,296
    float* wb2_f    = wb1_f + 55296;         // 55,296
    float* qkvbt_f  = wb2_f + 55296;         // 61,440  (640x192 bf16)
    float* projbt_f = qkvbt_f + 61440;       // 18,432  (192x192 bf16)
    float* f1bt_f   = projbt_f + 18432;      // 73,728  (768x192 bf16)
    float* f2bt_f   = f1bt_f + 73728;        // 73,728  (192x768 bf16)

    __hip_bfloat16* xn    = (__hip_bfloat16*)xn_f;
    __hip_bfloat16* y1b   = (__hip_bfloat16*)bufC;                  // 65536x64
    __hip_bfloat16* qkvC  = (__hip_bfloat16*)bufC;                  // RATTx576
    __hip_bfloat16* attnC = (__hip_bfloat16*)(bufC + attnCoff);     // 6xRATTx32 planar
    __hip_bfloat16* h1    = (__hip_bfloat16*)bufC;                  // (merged: 65536, else 32768)x768
    __hip_bfloat16* rpbM   = (__hip_bfloat16*)rpbM_f;
    __hip_bfloat16* wb1    = (__hip_bfloat16*)wb1_f;
    __hip_bfloat16* wb2    = (__hip_bfloat16*)wb2_f;
    __hip_bfloat16* qkvbt  = (__hip_bfloat16*)qkvbt_f;
    __hip_bfloat16* projbt = (__hip_bfloat16*)projbt_f;
    __hip_bfloat16* f1bt   = (__hip_bfloat16*)f1bt_f;
    __hip_bfloat16* f2bt   = (__hip_bfloat16*)f2bt_f;

    // ---- fused prep (741,376 items) ----
    prep_all_k<<<(741376 + 255) / 256, 256, 0, stream>>>(rpi, rpbt, mask, rpbM, c1w, wb1, c2w, wb2,
                                                         qkvw, qkvbt, projw, projbt,
                                                         f1w, f1bt, f2w, f2bt);

    // ---- LN1 -> bf16 ----
    ln_k<<<NTOK / 4, 256, 0, stream>>>(x, n1g, n1b, xn);

    // ---- CAB conv branch (MFMA): y2 lives in d_out ----
    mconv_k<8, 192, 60, 64, 1, 1><<<dim3(512, 1), 256, 0, stream>>>(xn, 192, wb1, c1b, y1b);
    mconv_k<16, 64, 180, 180, 0, 0><<<dim3(256, 3), 256, 0, stream>>>(y1b, 64, wb2, c2b, out);
    chansum_k<<<256, 192, 0, stream>>>(out, partials);
    ca_k<<<1, 256, 0, stream>>>(partials, ca1w, ca1b, ca2w, ca2b, scalep);

    // ---- attention branch (merged: 1 chunk of 256 windows; fallback: 2x128) ----
    for (int ck = 0; ck < nck; ++ck) {
        const int rowoff = ck * RATT;
        mgemm_k<3, 128><<<dim3(RATT / 128, 5), 256, 0, stream>>>(
            (const unsigned short*)xn, (const unsigned short*)qkvbt, qkvb, nullptr, nullptr,
            qkvC, 192, 540, 576, rowoff);
        attn10_k<<<dim3(RATT / 256, 6), 256, 0, stream>>>(qkvC, rpbM, attnC, rowoff / 256, RATT);
        mgemm_k<5, 64><<<dim3(RATT / 128, 3), 256, 0, stream>>>(
            (const unsigned short*)attnC, (const unsigned short*)projbt, projb, x, scalep,
            out, 192, 180, RATT, rowoff);
    }

    // ---- LN2 (x2 in d_out) -> bf16 xm ----
    ln_k<<<NTOK / 4, 256, 0, stream>>>(out, n2g, n2b, xn);

    // ---- MLP (merged: single pass over all 65536 rows; h1 fits bufC exactly) ----
    const int nmlp = merged ? 1 : 2;
    const int RM = merged ? NTOK : RCHUNK;
    for (int ck = 0; ck < nmlp; ++ck) {
        const int rowoff = ck * RM;
        mgemm_k<1, 128><<<dim3(RM / 128, 6), 256, 0, stream>>>(
            (const unsigned short*)(xn + (size_t)rowoff * KP1), (const unsigned short*)f1bt,
            f1b, nullptr, nullptr, h1, 192, 720, 768, 0);
        mgemm_k<2, 64><<<dim3(RM / 128, 3), 256, 0, stream>>>(
            (const unsigned short*)h1, (const unsigned short*)f2bt, f2b,
            out + (size_t)rowoff * 180, nullptr, out + (size_t)rowoff * 180, 768, 180, 180, 0);
    }
}

// Round 7
// 710.345 us; speedup vs baseline: 1.0542x; 1.0542x over previous
//
#include <hip/hip_runtime.h>
#include <hip/hip_bf16.h>
#include <math.h>
#include <type_traits>

#define NTOK 65536
#define C 180
#define KP1 192      // padded K for C=180
#define RCHUNK 32768 // rows per chunk (128 windows) for the MLP fallback
#define LOG2E 1.4426950408889634f

typedef __attribute__((ext_vector_type(8))) __bf16 bf16x8;
typedef __attribute__((ext_vector_type(4))) float floatx4;

__device__ __forceinline__ float gelu_f(float v) {
    return 0.5f * v * (1.f + erff(v * 0.7071067811865475f));
}
__device__ __forceinline__ float bflo(unsigned int u) { return __uint_as_float(u << 16); }
__device__ __forceinline__ float bfhi(unsigned int u) { return __uint_as_float(u & 0xffff0000u); }

// window-row (shifted-window order) -> pixel row index in [0, 65536)
__device__ __forceinline__ int win2pix(int wrow) {
    int wi = wrow >> 8, ni = wrow & 255;
    int r2 = ((wi >> 4) << 4) | (ni >> 4);
    int c2 = ((wi & 15) << 4) | (ni & 15);
    int r = (r2 + 8) & 255, c = (c2 + 8) & 255;
    return (r << 8) | c;
}

// ---------------- LayerNorm: fp32 in (stride 180) -> bf16 out (stride 192, zero pad) -----------
__global__ __launch_bounds__(256) void ln_k(const float* __restrict__ x,
                                            const float* __restrict__ g,
                                            const float* __restrict__ b,
                                            __hip_bfloat16* __restrict__ y) {
    const int wav = threadIdx.x >> 6;
    const int lane = threadIdx.x & 63;
    const int row = blockIdx.x * 4 + wav;
    const float* xr = x + (size_t)row * C;
    float v0 = xr[lane];
    float v1 = xr[lane + 64];
    float v2 = (lane < C - 128) ? xr[lane + 128] : 0.f;
    float sum = v0 + v1 + v2;
    float sq = v0 * v0 + v1 * v1 + v2 * v2;
#pragma unroll
    for (int off = 32; off >= 1; off >>= 1) {
        sum += __shfl_xor(sum, off, 64);
        sq += __shfl_xor(sq, off, 64);
    }
    const float mu = sum * (1.f / C);
    const float var = sq * (1.f / C) - mu * mu;
    const float rstd = rsqrtf(var + 1e-5f);
    __hip_bfloat16* yr = y + (size_t)row * KP1;
#pragma unroll
    for (int e = 0; e < 3; ++e) {
        int col = lane + 64 * e;
        float val = 0.f;
        if (col < C) {
            float vv = (e == 0) ? v0 : (e == 1 ? v1 : v2);
            val = (vv - mu) * rstd * g[col] + b[col];
        }
        yr[col] = __float2bfloat16(val);
    }
}

// ---------------- fused weight/bias prep (one dispatch) ----------------
__device__ __forceinline__ void wconv_item(const float* __restrict__ w,
                                           __hip_bfloat16* __restrict__ wb,
                                           int O, int I, int OCP, int KP, int idx) {
    int tap = idx / (OCP * KP);
    int rem = idx - tap * (OCP * KP);
    int oc = rem / KP, ch = rem - oc * KP;
    float v = (oc < O && ch < I) ? w[((size_t)(oc * I + ch)) * 9 + tap] : 0.f;
    wb[idx] = __float2bfloat16(v);
}
__device__ __forceinline__ void wprep_item(const float* __restrict__ w,
                                           __hip_bfloat16* __restrict__ bt,
                                           int K, int N, int KPd, int idx) {
    int n = idx / KPd, k = idx - n * KPd;
    float v = (n < N && k < K) ? w[(size_t)k * N + n] : 0.f;
    bt[idx] = __float2bfloat16(v);
}
// ranges: [0,65536) rpbM (4 types x 6 heads fused rpb+mask, pre-scaled by log2e for exp2) |
//         +110592 wconv1 | +110592 wconv2 | +122880 qkv | +36864 proj | +147456 f1 |
//         +147456 f2   total 741,376
__global__ void prep_all_k(const int* __restrict__ rpi, const float* __restrict__ table,
                           const float* __restrict__ mask,
                           __hip_bfloat16* __restrict__ rpbM,
                           const float* __restrict__ c1w, __hip_bfloat16* __restrict__ wb1,
                           const float* __restrict__ c2w, __hip_bfloat16* __restrict__ wb2,
                           const float* __restrict__ qkvw, __hip_bfloat16* __restrict__ qkvbt,
                           const float* __restrict__ projw, __hip_bfloat16* __restrict__ projbt,
                           const float* __restrict__ f1w, __hip_bfloat16* __restrict__ f1bt,
                           const float* __restrict__ f2w, __hip_bfloat16* __restrict__ f2bt) {
    int idx = blockIdx.x * 256 + threadIdx.x;
    if (idx < 65536) {
        int t = rpi[idx];
        // 4 distinct shifted-window mask patterns: interior / right col / bottom row / corner.
        float m1 = mask[(size_t)15 * 65536 + idx];
        float m2 = mask[(size_t)240 * 65536 + idx];
        float m3 = mask[(size_t)255 * 65536 + idx];
#pragma unroll
        for (int h = 0; h < 6; ++h) {
            float base = table[t * 6 + h];
            rpbM[((size_t)(0 * 6 + h)) * 65536 + idx] = __float2bfloat16(base * LOG2E);
            rpbM[((size_t)(1 * 6 + h)) * 65536 + idx] = __float2bfloat16((base + m1) * LOG2E);
            rpbM[((size_t)(2 * 6 + h)) * 65536 + idx] = __float2bfloat16((base + m2) * LOG2E);
            rpbM[((size_t)(3 * 6 + h)) * 65536 + idx] = __float2bfloat16((base + m3) * LOG2E);
        }
        return;
    }
    idx -= 65536;
    if (idx < 110592) { wconv_item(c1w, wb1, 60, 180, 64, 192, idx); return; }
    idx -= 110592;
    if (idx < 110592) { wconv_item(c2w, wb2, 180, 60, 192, 64, idx); return; }
    idx -= 110592;
    if (idx < 122880) { wprep_item(qkvw, qkvbt, 180, 540, 192, idx); return; }
    idx -= 122880;
    if (idx < 36864) { wprep_item(projw, projbt, 180, 180, 192, idx); return; }
    idx -= 36864;
    if (idx < 147456) { wprep_item(f1w, f1bt, 180, 720, 192, idx); return; }
    idx -= 147456;
    if (idx < 147456) { wprep_item(f2w, f2bt, 720, 180, 768, idx); return; }
}

// ---------------- MFMA implicit-GEMM conv 3x3, NHWC bf16 in, pad 1 ----------------
template <int TH, int CINP, int COUT, int OSTR, int ACT, int OUTBF>
__global__ __launch_bounds__(256) void mconv_k(const __hip_bfloat16* __restrict__ in, int istr,
                                               const __hip_bfloat16* __restrict__ wb,
                                               const float* __restrict__ bias,
                                               void* __restrict__ outp) {
    constexpr int MI = TH / 4;
    __shared__ __hip_bfloat16 sP[(TH + 2) * 18 * 40];
    __shared__ __hip_bfloat16 sW[9 * 64 * 40];
    const int tid = threadIdx.x;
    const int tr0 = (blockIdx.x >> 4) * TH, tc0 = (blockIdx.x & 15) * 16;
    const int ocbase = blockIdx.y * 64;
    const int w = tid >> 6, lane = tid & 63, fr = lane & 15, q = lane >> 4;
    constexpr int OCP = ((COUT + 63) / 64) * 64;
    floatx4 acc[MI][4] = {};
    for (int c0 = 0; c0 < CINP; c0 += 32) {
        for (int l = tid; l < (TH + 2) * 18 * 4; l += 256) {
            int pos = l >> 2, part = l & 3;
            int pr = pos / 18, pc = pos - pr * 18;
            int gr = tr0 + pr - 1, gc = tc0 + pc - 1;
            float4 v = make_float4(0.f, 0.f, 0.f, 0.f);
            if (gr >= 0 && gr < 256 && gc >= 0 && gc < 256)
                v = *(const float4*)(in + (size_t)(gr * 256 + gc) * istr + c0 + part * 8);
            *(float4*)(sP + pos * 40 + part * 8) = v;
        }
        for (int l = tid; l < 9 * 64 * 4; l += 256) {
            int part = l & 3, oc = (l >> 2) & 63, tap = l >> 8;
            *(float4*)(sW + tap * 2560 + oc * 40 + part * 8) =
                *(const float4*)(wb + (size_t)(tap * OCP + ocbase + oc) * CINP + c0 + part * 8);
        }
        __syncthreads();
#pragma unroll
        for (int tap = 0; tap < 9; ++tap) {
            const int dy = tap / 3, dx = tap - 3 * (tap / 3);
            bf16x8 af[MI], bw[4];
#pragma unroll
            for (int mi = 0; mi < MI; ++mi) {
                int pr = MI * w + mi + dy, pc = fr + dx;
                af[mi] = *(const bf16x8*)(sP + (pr * 18 + pc) * 40 + q * 8);
            }
#pragma unroll
            for (int nj = 0; nj < 4; ++nj)
                bw[nj] = *(const bf16x8*)(sW + tap * 2560 + (nj * 16 + fr) * 40 + q * 8);
#pragma unroll
            for (int mi = 0; mi < MI; ++mi)
#pragma unroll
                for (int nj = 0; nj < 4; ++nj)
                    acc[mi][nj] =
                        __builtin_amdgcn_mfma_f32_16x16x32_bf16(af[mi], bw[nj], acc[mi][nj], 0, 0, 0);
        }
        __syncthreads();
    }
#pragma unroll
    for (int mi = 0; mi < MI; ++mi) {
#pragma unroll
        for (int r = 0; r < 4; ++r) {
            const int irow = tr0 + MI * w + mi;
            const int icol = tc0 + q * 4 + r;
            const size_t obase = (size_t)(irow * 256 + icol) * OSTR + ocbase;
#pragma unroll
            for (int nj = 0; nj < 4; ++nj) {
                int oc = ocbase + nj * 16 + fr;
                float bv = (oc < COUT) ? bias[oc] : 0.f;
                float v = acc[mi][nj][r] + bv;
                if (ACT) v = gelu_f(v);
                if (OUTBF) {
                    ((__hip_bfloat16*)outp)[obase + nj * 16 + fr] = __float2bfloat16(v);
                } else {
                    if (oc < COUT) ((float*)outp)[obase + nj * 16 + fr] = v;
                }
            }
        }
    }
}

// ---------------- channel sums ----------------
__global__ __launch_bounds__(192) void chansum_k(const float* __restrict__ y2,
                                                 float* __restrict__ partials) {
    const int tid = threadIdx.x;
    if (tid >= C) return;
    const size_t base = (size_t)blockIdx.x * 256 * C;
    float s = 0.f;
    for (int p = 0; p < 256; ++p) s += y2[base + (size_t)p * C + tid];
    partials[blockIdx.x * C + tid] = s;
}

// ---------------- channel attention MLP (1 block) ----------------
__global__ __launch_bounds__(256) void ca_k(const float* __restrict__ partials,
                                            const float* __restrict__ w1, const float* __restrict__ b1,
                                            const float* __restrict__ w2, const float* __restrict__ b2,
                                            float* __restrict__ scale) {
    __shared__ float mean[C];
    __shared__ float s1[6];
    const int tid = threadIdx.x;
    if (tid < C) {
        float s = 0.f;
        for (int b_ = 0; b_ < 256; ++b_) s += partials[b_ * C + tid];
        mean[tid] = s * (1.f / 65536.f);
    }
    __syncthreads();
    if (tid < 6) {
        float s = b1[tid];
        for (int ch = 0; ch < C; ++ch) s += mean[ch] * w1[tid * C + ch];
        s1[tid] = fmaxf(s, 0.f);
    }
    __syncthreads();
    if (tid < C) {
        float s = b2[tid];
#pragma unroll
        for (int j = 0; j < 6; ++j) s += s1[j] * w2[tid * 6 + j];
        scale[tid] = 1.f / (1.f + __expf(-s));
    }
}

// ---------------- bf16 MFMA GEMM: BM=128, BN in {64,128}, BK=32, 4 waves (2x2) ----------
// Grid is (M-blocks, N-blocks): m0 from blockIdx.x so linear_bid%8 == blockIdx.x%8 -> each
// XCD keeps a stable A working set across all N-passes (A re-reads become L2 hits).
// Plain stores: outputs feed the NEXT dispatch (round-4 lesson: nt stores cost +128 us).
template <int MODE, int BN>
__global__ __launch_bounds__(256) void mgemm_k(const unsigned short* __restrict__ A,
                                               const unsigned short* __restrict__ BT,
                                               const float* __restrict__ bias,
                                               const float* __restrict__ xres,
                                               const float* __restrict__ scale,
                                               void* __restrict__ Cout,
                                               int KPd, int N, int cstride, int rowoff) {
    __shared__ unsigned short As[128 * 40];
    __shared__ unsigned short Bs[BN * 40];
    constexpr int NJ = BN / 32;
    const int tid = threadIdx.x;
    const int m0 = blockIdx.x * 128, n0 = blockIdx.y * BN;
    const int arow_l = tid >> 1;
    const int akofs = (tid & 1) * 16;
    size_t arow;
    if (MODE == 3)
        arow = (size_t)win2pix(rowoff + m0 + arow_l) * KPd;
    else
        arow = (size_t)(m0 + arow_l) * KPd;
    const int brow_l = (BN == 128) ? (tid >> 1) : (tid >> 2);
    const int bkofs = (BN == 128) ? ((tid & 1) * 16) : ((tid & 3) * 8);
    const size_t brow = (size_t)(n0 + brow_l) * KPd;
    const int wave = tid >> 6, lane = tid & 63;
    const int wm = (wave & 1) * 64, wn = (wave >> 1) * (BN / 2);
    const int fr = lane & 15, q = lane >> 4;
    floatx4 acc[4][NJ] = {};
    for (int k0 = 0; k0 < KPd; k0 += 32) {
        if (MODE == 5) {
            const unsigned short* Ap = A + ((size_t)(k0 >> 5) * cstride + (m0 + arow_l)) * 32;
            *(float4*)(&As[arow_l * 40 + akofs]) = *(const float4*)(Ap + akofs);
            *(float4*)(&As[arow_l * 40 + akofs + 8]) = *(const float4*)(Ap + akofs + 8);
        } else {
            *(float4*)(&As[arow_l * 40 + akofs]) = *(const float4*)(A + arow + k0 + akofs);
            *(float4*)(&As[arow_l * 40 + akofs + 8]) = *(const float4*)(A + arow + k0 + akofs + 8);
        }
        if (BN == 128) {
            *(float4*)(&Bs[brow_l * 40 + bkofs]) = *(const float4*)(BT + brow + k0 + bkofs);
            *(float4*)(&Bs[brow_l * 40 + bkofs + 8]) = *(const float4*)(BT + brow + k0 + bkofs + 8);
        } else {
            *(float4*)(&Bs[brow_l * 40 + bkofs]) = *(const float4*)(BT + brow + k0 + bkofs);
        }
        __syncthreads();
        bf16x8 af[4], fB[NJ];
#pragma unroll
        for (int i = 0; i < 4; ++i)
            af[i] = *(const bf16x8*)(&As[(wm + i * 16 + fr) * 40 + q * 8]);
#pragma unroll
        for (int j = 0; j < NJ; ++j)
            fB[j] = *(const bf16x8*)(&Bs[(wn + j * 16 + fr) * 40 + q * 8]);
#pragma unroll
        for (int i = 0; i < 4; ++i)
#pragma unroll
            for (int j = 0; j < NJ; ++j)
                acc[i][j] = __builtin_amdgcn_mfma_f32_16x16x32_bf16(af[i], fB[j], acc[i][j], 0, 0, 0);
        __syncthreads();
    }
#pragma unroll
    for (int i = 0; i < 4; ++i) {
#pragma unroll
        for (int r = 0; r < 4; ++r) {
            const int grow = m0 + wm + i * 16 + q * 4 + r;
            int pix = 0;
            if (MODE == 5) pix = win2pix(rowoff + grow);
#pragma unroll
            for (int j = 0; j < NJ; ++j) {
                const int col = n0 + wn + j * 16 + fr;
                float v = acc[i][j][r];
                if (MODE == 1 || MODE == 3) {
                    if (col < cstride) {
                        float vv = 0.f;
                        if (col < N) {
                            vv = v + bias[col];
                            if (MODE == 1) vv = gelu_f(vv);
                        }
                        ((__hip_bfloat16*)Cout)[(size_t)grow * cstride + col] = __float2bfloat16(vv);
                    }
                } else if (MODE == 2) {
                    if (col < N) {
                        float* o = (float*)Cout;
                        size_t ix = (size_t)grow * 180 + col;
                        o[ix] = v + bias[col] + xres[ix];
                    }
                } else if (MODE == 5) {
                    if (col < N) {
                        float* o = (float*)Cout;
                        size_t ix = (size_t)pix * 180 + col;
                        o[ix] = xres[ix] + v + bias[col] + o[ix] * scale[col] * 0.01f;
                    }
                }
            }
        }
    }
}

// ---------------- MFMA flash attention v11 ----------------
// = v9 + rb double-buffer done RIGHT: two NAMED buffers rbA/rbB passed as array-reference
// params to a compile-time-unrolled body (integral_constant nc) -> zero runtime indexing,
// so the buffers stay in VGPRs (round-2/round-6 lesson: rb[cur] demotes to scratch, rule #20).
// Keeps exp2 path (rpbM pre-scaled by log2e) and the 32KB swizzled LDS.
__global__ __launch_bounds__(256, 4) void attn11_k(const __hip_bfloat16* __restrict__ qkv,  // [R][576]
                                                   const __hip_bfloat16* __restrict__ rpbM, // [typ][h][qry][key]
                                                   __hip_bfloat16* __restrict__ attn_out,   // [6][rows][32]
                                                   int wbase, int rows) {
    const int wl = blockIdx.x, h = blockIdx.y;
    const int wig = wbase + wl;
    const int typ = (((wig >> 4) == 15) ? 2 : 0) + (((wig & 15) == 15) ? 1 : 0);
    const int tid = threadIdx.x;
    const int w = tid >> 6, lane = tid & 63;
    const int fr = lane & 15, q = lane >> 4;
    // kk: logical [key][d0..31], byte = key*64 + ((slot ^ (key&3))<<4) + inslot, slot=d>>3
    // vT: logical [d][key0..255], byte = d*512 + (((key>>3) ^ d)<<4) + (key&7)*2
    __shared__ __hip_bfloat16 kk[256 * 32];
    __shared__ __hip_bfloat16 vT[32 * 256];

    union UB2 { unsigned int u; __hip_bfloat162 h2; };
    union U8 { unsigned int u[4]; bf16x8 v; };

    // ---- Q fragments (global, independent of LDS) ----
    const int rowbase = wl * 256 + w * 64;
    bf16x8 qf[4];
#pragma unroll
    for (int qi = 0; qi < 4; ++qi) {
        const unsigned int* p32 =
            (const unsigned int*)(qkv + (size_t)(rowbase + qi * 16 + fr) * 576 + h * 30);
        U8 t;
#pragma unroll
        for (int jj = 0; jj < 4; ++jj) t.u[jj] = p32[q * 4 + jj];
        qf[qi] = t.v;
    }

    // ---- rb prefetch for nc=0 into rbA: issue before staging, latency hides under drain ----
    const __hip_bfloat16* rpbh = rpbM + ((size_t)(typ * 6 + h)) * 65536;
    uint2 rbA[4][4], rbB[4][4];
#pragma unroll
    for (int qi = 0; qi < 4; ++qi) {
        const size_t qoff = ((size_t)(w * 64 + qi * 16 + fr)) * 256 + q * 4;
#pragma unroll
        for (int ki = 0; ki < 4; ++ki)
            rbA[qi][ki] = *(const uint2*)(rpbh + qoff + ki * 16);
    }

    // ---- K/V staging into swizzled LDS ----
    for (int l = tid; l < 256 * 15; l += 256) {
        int key = l / 15, dw_ = l - key * 15;
        const unsigned int* ks =
            (const unsigned int*)(qkv + (size_t)(wl * 256 + key) * 576 + 180 + h * 30);
        unsigned int kv = ks[dw_];
        *(unsigned int*)((char*)kk + key * 64 + (((dw_ >> 2) ^ (key & 3)) << 4) + ((dw_ & 3) << 2)) = kv;
        UB2 vv; vv.u = ks[90 + dw_];
        const int d0 = 2 * dw_, d1 = d0 + 1;
        *(__hip_bfloat16*)((char*)vT + d0 * 512 + (((key >> 3) ^ d0) << 4) + ((key & 7) << 1)) = vv.h2.x;
        *(__hip_bfloat16*)((char*)vT + d1 * 512 + (((key >> 3) ^ d1) << 4) + ((key & 7) << 1)) = vv.h2.y;
    }
    // zero pads: kk d=30,31 (dword 15 of each key row); vT d=30,31 all keys
    *(unsigned int*)((char*)kk + tid * 64 + ((3 ^ (tid & 3)) << 4) + 12) = 0u;
    for (int l = tid; l < 2 * 256; l += 256) {
        int d = 30 + (l >> 8), key = l & 255;
        *(__hip_bfloat16*)((char*)vT + d * 512 + (((key >> 3) ^ d) << 4) + ((key & 7) << 1)) =
            __float2bfloat16(0.f);
    }
    __syncthreads();

    const float SC2 = 0.26339891239045137f;  // (1/sqrt(30)) * log2(e)
    float lsum[4] = {};
    floatx4 o_[4][2] = {};
    const int srcA = fr + ((q & 1) << 5);
    const int srcB = srcA + 16;

    // body(nc): prefetch (nc+1) biases into rbP, compute with rbU. All indices literal.
    auto body = [&](auto NCC, auto PREC, uint2 (&rbU)[4][4], uint2 (&rbP)[4][4]) {
        constexpr int nc = decltype(NCC)::value;
        constexpr bool PRE = decltype(PREC)::value;
        if constexpr (PRE) {
#pragma unroll
            for (int qi = 0; qi < 4; ++qi) {
                const size_t qoff =
                    ((size_t)(w * 64 + qi * 16 + fr)) * 256 + (nc + 1) * 64 + q * 4;
#pragma unroll
                for (int ki = 0; ki < 4; ++ki)
                    rbP[qi][ki] = *(const uint2*)(rpbh + qoff + ki * 16);
            }
        }
        bf16x8 kf[4];
#pragma unroll
        for (int ki = 0; ki < 4; ++ki) {
            const int key = nc * 64 + ki * 16 + fr;
            kf[ki] = *(const bf16x8*)((const char*)kk + key * 64 + ((q ^ (fr & 3)) << 4));
        }
        unsigned int dw[4][4][2];
#pragma unroll
        for (int qi = 0; qi < 4; ++qi) {
            floatx4 s_[4] = {};
#pragma unroll
            for (int ki = 0; ki < 4; ++ki)
                s_[ki] = __builtin_amdgcn_mfma_f32_16x16x32_bf16(kf[ki], qf[qi], s_[ki], 0, 0, 0);
#pragma unroll
            for (int ki = 0; ki < 4; ++ki) {
                uint2 rbv = rbU[qi][ki];
                float b0 = bflo(rbv.x), b1 = bfhi(rbv.x), b2 = bflo(rbv.y), b3 = bfhi(rbv.y);
                float p0 = exp2f(fmaf(s_[ki][0], SC2, b0));
                float p1 = exp2f(fmaf(s_[ki][1], SC2, b1));
                float p2 = exp2f(fmaf(s_[ki][2], SC2, b2));
                float p3 = exp2f(fmaf(s_[ki][3], SC2, b3));
                lsum[qi] += (p0 + p1) + (p2 + p3);
                __hip_bfloat162 lo = {__float2bfloat16(p0), __float2bfloat16(p1)};
                __hip_bfloat162 hi = {__float2bfloat16(p2), __float2bfloat16(p3)};
                UB2 ul, uh; ul.h2 = lo; uh.h2 = hi;
                dw[ki][qi][0] = ul.u;
                dw[ki][qi][1] = uh.u;
            }
        }
#pragma unroll
        for (int kc = 0; kc < 2; ++kc) {
            bf16x8 pa[4];
#pragma unroll
            for (int mi = 0; mi < 4; ++mi) {
                unsigned g0 = __shfl((int)dw[2 * kc][mi][0], srcA, 64);
                unsigned g1 = __shfl((int)dw[2 * kc][mi][1], srcA, 64);
                unsigned g2 = __shfl((int)dw[2 * kc][mi][0], srcB, 64);
                unsigned g3 = __shfl((int)dw[2 * kc][mi][1], srcB, 64);
                unsigned h0 = __shfl((int)dw[2 * kc + 1][mi][0], srcA, 64);
                unsigned h1 = __shfl((int)dw[2 * kc + 1][mi][1], srcA, 64);
                unsigned h2 = __shfl((int)dw[2 * kc + 1][mi][0], srcB, 64);
                unsigned h3 = __shfl((int)dw[2 * kc + 1][mi][1], srcB, 64);
                U8 t;
                const bool lo = (q < 2);
                t.u[0] = lo ? g0 : h0;
                t.u[1] = lo ? g1 : h1;
                t.u[2] = lo ? g2 : h2;
                t.u[3] = lo ? g3 : h3;
                pa[mi] = t.v;
            }
            bf16x8 vb[2];
#pragma unroll
            for (int dj = 0; dj < 2; ++dj) {
                const int d = dj * 16 + fr;
                vb[dj] = *(const bf16x8*)((const char*)vT + d * 512 +
                                          (((nc * 8 + kc * 4 + q) ^ d) << 4));
            }
#pragma unroll
            for (int mi = 0; mi < 4; ++mi)
#pragma unroll
                for (int dj = 0; dj < 2; ++dj)
                    o_[mi][dj] =
                        __builtin_amdgcn_mfma_f32_16x16x32_bf16(pa[mi], vb[dj], o_[mi][dj], 0, 0, 0);
        }
    };
    body(std::integral_constant<int, 0>{}, std::true_type{}, rbA, rbB);
    body(std::integral_constant<int, 1>{}, std::true_type{}, rbB, rbA);
    body(std::integral_constant<int, 2>{}, std::true_type{}, rbA, rbB);
    body(std::integral_constant<int, 3>{}, std::false_type{}, rbB, rbA);

    // row sums: reduce across q-groups, redistribute via shfl
#pragma unroll
    for (int qi = 0; qi < 4; ++qi) {
        lsum[qi] += __shfl_xor(lsum[qi], 16, 64);
        lsum[qi] += __shfl_xor(lsum[qi], 32, 64);
    }
    __hip_bfloat16* plane = attn_out + (size_t)h * rows * 32;
#pragma unroll
    for (int mi = 0; mi < 4; ++mi) {
#pragma unroll
        for (int r = 0; r < 4; ++r) {
            float tot = __shfl(lsum[mi], q * 4 + r, 64);
            float inv = 1.f / tot;
            const int row_local = rowbase + mi * 16 + q * 4 + r;
            __hip_bfloat16* orow = plane + (size_t)row_local * 32;
#pragma unroll
            for (int dj = 0; dj < 2; ++dj) {
                int d = dj * 16 + fr;
                float val = (d < 30) ? o_[mi][dj][r] * inv : 0.f;
                orow[d] = __float2bfloat16(val);
            }
        }
    }
}

extern "C" void kernel_launch(void* const* d_in, const int* in_sizes, int n_in, void* d_out,
                              int out_size, void* d_ws, size_t ws_size, hipStream_t stream) {
    (void)in_sizes; (void)n_in; (void)out_size;
    const float* x = (const float*)d_in[0];
    const int* rpi = (const int*)d_in[3];
    const float* mask = (const float*)d_in[4];
    const float* n1g = (const float*)d_in[5];
    const float* n1b = (const float*)d_in[6];
    const float* qkvw = (const float*)d_in[7];
    const float* qkvb = (const float*)d_in[8];
    const float* rpbt = (const float*)d_in[9];
    const float* projw = (const float*)d_in[10];
    const float* projb = (const float*)d_in[11];
    const float* c1w = (const float*)d_in[12];
    const float* c1b = (const float*)d_in[13];
    const float* c2w = (const float*)d_in[14];
    const float* c2b = (const float*)d_in[15];
    const float* ca1w = (const float*)d_in[16];
    const float* ca1b = (const float*)d_in[17];
    const float* ca2w = (const float*)d_in[18];
    const float* ca2b = (const float*)d_in[19];
    const float* n2g = (const float*)d_in[20];
    const float* n2b = (const float*)d_in[21];
    const float* f1w = (const float*)d_in[22];
    const float* f1b = (const float*)d_in[23];
    const float* f2w = (const float*)d_in[24];
    const float* f2b = (const float*)d_in[25];

    float* ws = (float*)d_ws;
    float* out = (float*)d_out;  // y2 -> x2 -> final output (in place, disjoint phases)

    // Merged attention path needs 130,511,616 B of workspace; fall back to 2-chunk if smaller.
    const int merged = (ws_size >= 130511616ull) ? 1 : 0;
    const int RATT = merged ? 65536 : 32768;
    const int nck = merged ? 1 : 2;
    const size_t bufCf = merged ? 25165824u : 12582912u;   // floats in the big shared region
    const size_t attnCoff = merged ? 18874368u : 9437184u; // float offset of attnC inside bufC

    // workspace layout (floats; offsets 16B-aligned)
    float* xn_f     = ws;                    // 6,291,456 (65536x192 bf16)
    float* bufC     = xn_f + 6291456;        // y1b | qkvC+attnC | h1 (all bf16)
    float* partials = bufC + bufCf;          // 46,080
    float* scalep   = partials + 46080;      // 192
    float* rpbM_f   = scalep + 192;          // 786,432 (4x6x65536 bf16, rpb+mask fused)
    float* wb1_f    = rpbM_f + 786432;       // 55,296
    float* wb2_f    = wb1_f + 55296;         // 55,296
    float* qkvbt_f  = wb2_f + 55296;         // 61,440  (640x192 bf16)
    float* projbt_f = qkvbt_f + 61440;       // 18,432  (192x192 bf16)
    float* f1bt_f   = projbt_f + 18432;      // 73,728  (768x192 bf16)
    float* f2bt_f   = f1bt_f + 73728;        // 73,728  (192x768 bf16)

    __hip_bfloat16* xn    = (__hip_bfloat16*)xn_f;
    __hip_bfloat16* y1b   = (__hip_bfloat16*)bufC;                  // 65536x64
    __hip_bfloat16* qkvC  = (__hip_bfloat16*)bufC;                  // RATTx576
    __hip_bfloat16* attnC = (__hip_bfloat16*)(bufC + attnCoff);     // 6xRATTx32 planar
    __hip_bfloat16* h1    = (__hip_bfloat16*)bufC;                  // (merged: 65536, else 32768)x768
    __hip_bfloat16* rpbM   = (__hip_bfloat16*)rpbM_f;
    __hip_bfloat16* wb1    = (__hip_bfloat16*)wb1_f;
    __hip_bfloat16* wb2    = (__hip_bfloat16*)wb2_f;
    __hip_bfloat16* qkvbt  = (__hip_bfloat16*)qkvbt_f;
    __hip_bfloat16* projbt = (__hip_bfloat16*)projbt_f;
    __hip_bfloat16* f1bt   = (__hip_bfloat16*)f1bt_f;
    __hip_bfloat16* f2bt   = (__hip_bfloat16*)f2bt_f;

    // ---- fused prep (741,376 items) ----
    prep_all_k<<<(741376 + 255) / 256, 256, 0, stream>>>(rpi, rpbt, mask, rpbM, c1w, wb1, c2w, wb2,
                                                         qkvw, qkvbt, projw, projbt,
                                                         f1w, f1bt, f2w, f2bt);

    // ---- LN1 -> bf16 ----
    ln_k<<<NTOK / 4, 256, 0, stream>>>(x, n1g, n1b, xn);

    // ---- CAB conv branch (MFMA): y2 lives in d_out ----
    mconv_k<8, 192, 60, 64, 1, 1><<<dim3(512, 1), 256, 0, stream>>>(xn, 192, wb1, c1b, y1b);
    mconv_k<16, 64, 180, 180, 0, 0><<<dim3(256, 3), 256, 0, stream>>>(y1b, 64, wb2, c2b, out);
    chansum_k<<<256, 192, 0, stream>>>(out, partials);
    ca_k<<<1, 256, 0, stream>>>(partials, ca1w, ca1b, ca2w, ca2b, scalep);

    // ---- attention branch (merged: 1 chunk of 256 windows; fallback: 2x128) ----
    for (int ck = 0; ck < nck; ++ck) {
        const int rowoff = ck * RATT;
        mgemm_k<3, 128><<<dim3(RATT / 128, 5), 256, 0, stream>>>(
            (const unsigned short*)xn, (const unsigned short*)qkvbt, qkvb, nullptr, nullptr,
            qkvC, 192, 540, 576, rowoff);
        attn11_k<<<dim3(RATT / 256, 6), 256, 0, stream>>>(qkvC, rpbM, attnC, rowoff / 256, RATT);
        mgemm_k<5, 64><<<dim3(RATT / 128, 3), 256, 0, stream>>>(
            (const unsigned short*)attnC, (const unsigned short*)projbt, projb, x, scalep,
            out, 192, 180, RATT, rowoff);
    }

    // ---- LN2 (x2 in d_out) -> bf16 xm ----
    ln_k<<<NTOK / 4, 256, 0, stream>>>(out, n2g, n2b, xn);

    // ---- MLP (merged: single pass over all 65536 rows; h1 fits bufC exactly) ----
    const int nmlp = merged ? 1 : 2;
    const int RM = merged ? NTOK : RCHUNK;
    for (int ck = 0; ck < nmlp; ++ck) {
        const int rowoff = ck * RM;
        mgemm_k<1, 128><<<dim3(RM / 128, 6), 256, 0, stream>>>(
            (const unsigned short*)(xn + (size_t)rowoff * KP1), (const unsigned short*)f1bt,
            f1b, nullptr, nullptr, h1, 192, 720, 768, 0);
        mgemm_k<2, 64><<<dim3(RM / 128, 3), 256, 0, stream>>>(
            (const unsigned short*)h1, (const unsigned short*)f2bt, f2b,
            out + (size_t)rowoff * 180, nullptr, out + (size_t)rowoff * 180, 768, 180, 180, 0);
    }
}

// Round 8
// 624.362 us; speedup vs baseline: 1.1994x; 1.1377x over previous
//
#include <hip/hip_runtime.h>
#include <hip/hip_bf16.h>
#include <math.h>

#define NTOK 65536
#define C 180
#define KP1 192      // padded K for C=180
#define RCHUNK 32768 // rows per chunk (128 windows) for the MLP fallback
#define LOG2E 1.4426950408889634f

typedef __attribute__((ext_vector_type(8))) __bf16 bf16x8;
typedef __attribute__((ext_vector_type(4))) float floatx4;

__device__ __forceinline__ float gelu_f(float v) {
    return 0.5f * v * (1.f + erff(v * 0.7071067811865475f));
}
__device__ __forceinline__ float bflo(unsigned int u) { return __uint_as_float(u << 16); }
__device__ __forceinline__ float bfhi(unsigned int u) { return __uint_as_float(u & 0xffff0000u); }

// window-row (shifted-window order) -> pixel row index in [0, 65536)
__device__ __forceinline__ int win2pix(int wrow) {
    int wi = wrow >> 8, ni = wrow & 255;
    int r2 = ((wi >> 4) << 4) | (ni >> 4);
    int c2 = ((wi & 15) << 4) | (ni & 15);
    int r = (r2 + 8) & 255, c = (c2 + 8) & 255;
    return (r << 8) | c;
}

// ---------------- LayerNorm: fp32 in (stride 180) -> bf16 out (stride 192, zero pad) -----------
__global__ __launch_bounds__(256) void ln_k(const float* __restrict__ x,
                                            const float* __restrict__ g,
                                            const float* __restrict__ b,
                                            __hip_bfloat16* __restrict__ y) {
    const int wav = threadIdx.x >> 6;
    const int lane = threadIdx.x & 63;
    const int row = blockIdx.x * 4 + wav;
    const float* xr = x + (size_t)row * C;
    float v0 = xr[lane];
    float v1 = xr[lane + 64];
    float v2 = (lane < C - 128) ? xr[lane + 128] : 0.f;
    float sum = v0 + v1 + v2;
    float sq = v0 * v0 + v1 * v1 + v2 * v2;
#pragma unroll
    for (int off = 32; off >= 1; off >>= 1) {
        sum += __shfl_xor(sum, off, 64);
        sq += __shfl_xor(sq, off, 64);
    }
    const float mu = sum * (1.f / C);
    const float var = sq * (1.f / C) - mu * mu;
    const float rstd = rsqrtf(var + 1e-5f);
    __hip_bfloat16* yr = y + (size_t)row * KP1;
#pragma unroll
    for (int e = 0; e < 3; ++e) {
        int col = lane + 64 * e;
        float val = 0.f;
        if (col < C) {
            float vv = (e == 0) ? v0 : (e == 1 ? v1 : v2);
            val = (vv - mu) * rstd * g[col] + b[col];
        }
        yr[col] = __float2bfloat16(val);
    }
}

// ---------------- fused weight/bias prep (one dispatch) ----------------
__device__ __forceinline__ void wconv_item(const float* __restrict__ w,
                                           __hip_bfloat16* __restrict__ wb,
                                           int O, int I, int OCP, int KP, int idx) {
    int tap = idx / (OCP * KP);
    int rem = idx - tap * (OCP * KP);
    int oc = rem / KP, ch = rem - oc * KP;
    float v = (oc < O && ch < I) ? w[((size_t)(oc * I + ch)) * 9 + tap] : 0.f;
    wb[idx] = __float2bfloat16(v);
}
__device__ __forceinline__ void wprep_item(const float* __restrict__ w,
                                           __hip_bfloat16* __restrict__ bt,
                                           int K, int N, int KPd, int idx) {
    int n = idx / KPd, k = idx - n * KPd;
    float v = (n < N && k < K) ? w[(size_t)k * N + n] : 0.f;
    bt[idx] = __float2bfloat16(v);
}
// ranges: [0,65536) rpbM (4 types x 6 heads fused rpb+mask, pre-scaled by log2e for exp2) |
//         +110592 wconv1 | +110592 wconv2 | +122880 qkv | +36864 proj | +147456 f1 |
//         +147456 f2   total 741,376
__global__ void prep_all_k(const int* __restrict__ rpi, const float* __restrict__ table,
                           const float* __restrict__ mask,
                           __hip_bfloat16* __restrict__ rpbM,
                           const float* __restrict__ c1w, __hip_bfloat16* __restrict__ wb1,
                           const float* __restrict__ c2w, __hip_bfloat16* __restrict__ wb2,
                           const float* __restrict__ qkvw, __hip_bfloat16* __restrict__ qkvbt,
                           const float* __restrict__ projw, __hip_bfloat16* __restrict__ projbt,
                           const float* __restrict__ f1w, __hip_bfloat16* __restrict__ f1bt,
                           const float* __restrict__ f2w, __hip_bfloat16* __restrict__ f2bt) {
    int idx = blockIdx.x * 256 + threadIdx.x;
    if (idx < 65536) {
        int t = rpi[idx];
        // 4 distinct shifted-window mask patterns: interior / right col / bottom row / corner.
        float m1 = mask[(size_t)15 * 65536 + idx];
        float m2 = mask[(size_t)240 * 65536 + idx];
        float m3 = mask[(size_t)255 * 65536 + idx];
#pragma unroll
        for (int h = 0; h < 6; ++h) {
            float base = table[t * 6 + h];
            rpbM[((size_t)(0 * 6 + h)) * 65536 + idx] = __float2bfloat16(base * LOG2E);
            rpbM[((size_t)(1 * 6 + h)) * 65536 + idx] = __float2bfloat16((base + m1) * LOG2E);
            rpbM[((size_t)(2 * 6 + h)) * 65536 + idx] = __float2bfloat16((base + m2) * LOG2E);
            rpbM[((size_t)(3 * 6 + h)) * 65536 + idx] = __float2bfloat16((base + m3) * LOG2E);
        }
        return;
    }
    idx -= 65536;
    if (idx < 110592) { wconv_item(c1w, wb1, 60, 180, 64, 192, idx); return; }
    idx -= 110592;
    if (idx < 110592) { wconv_item(c2w, wb2, 180, 60, 192, 64, idx); return; }
    idx -= 110592;
    if (idx < 122880) { wprep_item(qkvw, qkvbt, 180, 540, 192, idx); return; }
    idx -= 122880;
    if (idx < 36864) { wprep_item(projw, projbt, 180, 180, 192, idx); return; }
    idx -= 36864;
    if (idx < 147456) { wprep_item(f1w, f1bt, 180, 720, 192, idx); return; }
    idx -= 147456;
    if (idx < 147456) { wprep_item(f2w, f2bt, 720, 180, 768, idx); return; }
}

// ---------------- MFMA implicit-GEMM conv 3x3, NHWC bf16 in, pad 1 ----------------
template <int TH, int CINP, int COUT, int OSTR, int ACT, int OUTBF>
__global__ __launch_bounds__(256) void mconv_k(const __hip_bfloat16* __restrict__ in, int istr,
                                               const __hip_bfloat16* __restrict__ wb,
                                               const float* __restrict__ bias,
                                               void* __restrict__ outp) {
    constexpr int MI = TH / 4;
    __shared__ __hip_bfloat16 sP[(TH + 2) * 18 * 40];
    __shared__ __hip_bfloat16 sW[9 * 64 * 40];
    const int tid = threadIdx.x;
    const int tr0 = (blockIdx.x >> 4) * TH, tc0 = (blockIdx.x & 15) * 16;
    const int ocbase = blockIdx.y * 64;
    const int w = tid >> 6, lane = tid & 63, fr = lane & 15, q = lane >> 4;
    constexpr int OCP = ((COUT + 63) / 64) * 64;
    floatx4 acc[MI][4] = {};
    for (int c0 = 0; c0 < CINP; c0 += 32) {
        for (int l = tid; l < (TH + 2) * 18 * 4; l += 256) {
            int pos = l >> 2, part = l & 3;
            int pr = pos / 18, pc = pos - pr * 18;
            int gr = tr0 + pr - 1, gc = tc0 + pc - 1;
            float4 v = make_float4(0.f, 0.f, 0.f, 0.f);
            if (gr >= 0 && gr < 256 && gc >= 0 && gc < 256)
                v = *(const float4*)(in + (size_t)(gr * 256 + gc) * istr + c0 + part * 8);
            *(float4*)(sP + pos * 40 + part * 8) = v;
        }
        for (int l = tid; l < 9 * 64 * 4; l += 256) {
            int part = l & 3, oc = (l >> 2) & 63, tap = l >> 8;
            *(float4*)(sW + tap * 2560 + oc * 40 + part * 8) =
                *(const float4*)(wb + (size_t)(tap * OCP + ocbase + oc) * CINP + c0 + part * 8);
        }
        __syncthreads();
#pragma unroll
        for (int tap = 0; tap < 9; ++tap) {
            const int dy = tap / 3, dx = tap - 3 * (tap / 3);
            bf16x8 af[MI], bw[4];
#pragma unroll
            for (int mi = 0; mi < MI; ++mi) {
                int pr = MI * w + mi + dy, pc = fr + dx;
                af[mi] = *(const bf16x8*)(sP + (pr * 18 + pc) * 40 + q * 8);
            }
#pragma unroll
            for (int nj = 0; nj < 4; ++nj)
                bw[nj] = *(const bf16x8*)(sW + tap * 2560 + (nj * 16 + fr) * 40 + q * 8);
#pragma unroll
            for (int mi = 0; mi < MI; ++mi)
#pragma unroll
                for (int nj = 0; nj < 4; ++nj)
                    acc[mi][nj] =
                        __builtin_amdgcn_mfma_f32_16x16x32_bf16(af[mi], bw[nj], acc[mi][nj], 0, 0, 0);
        }
        __syncthreads();
    }
#pragma unroll
    for (int mi = 0; mi < MI; ++mi) {
#pragma unroll
        for (int r = 0; r < 4; ++r) {
            const int irow = tr0 + MI * w + mi;
            const int icol = tc0 + q * 4 + r;
            const size_t obase = (size_t)(irow * 256 + icol) * OSTR + ocbase;
#pragma unroll
            for (int nj = 0; nj < 4; ++nj) {
                int oc = ocbase + nj * 16 + fr;
                float bv = (oc < COUT) ? bias[oc] : 0.f;
                float v = acc[mi][nj][r] + bv;
                if (ACT) v = gelu_f(v);
                if (OUTBF) {
                    ((__hip_bfloat16*)outp)[obase + nj * 16 + fr] = __float2bfloat16(v);
                } else {
                    if (oc < COUT) ((float*)outp)[obase + nj * 16 + fr] = v;
                }
            }
        }
    }
}

// ---------------- channel sums ----------------
__global__ __launch_bounds__(192) void chansum_k(const float* __restrict__ y2,
                                                 float* __restrict__ partials) {
    const int tid = threadIdx.x;
    if (tid >= C) return;
    const size_t base = (size_t)blockIdx.x * 256 * C;
    float s = 0.f;
    for (int p = 0; p < 256; ++p) s += y2[base + (size_t)p * C + tid];
    partials[blockIdx.x * C + tid] = s;
}

// ---------------- channel attention MLP (1 block) ----------------
__global__ __launch_bounds__(256) void ca_k(const float* __restrict__ partials,
                                            const float* __restrict__ w1, const float* __restrict__ b1,
                                            const float* __restrict__ w2, const float* __restrict__ b2,
                                            float* __restrict__ scale) {
    __shared__ float mean[C];
    __shared__ float s1[6];
    const int tid = threadIdx.x;
    if (tid < C) {
        float s = 0.f;
        for (int b_ = 0; b_ < 256; ++b_) s += partials[b_ * C + tid];
        mean[tid] = s * (1.f / 65536.f);
    }
    __syncthreads();
    if (tid < 6) {
        float s = b1[tid];
        for (int ch = 0; ch < C; ++ch) s += mean[ch] * w1[tid * C + ch];
        s1[tid] = fmaxf(s, 0.f);
    }
    __syncthreads();
    if (tid < C) {
        float s = b2[tid];
#pragma unroll
        for (int j = 0; j < 6; ++j) s += s1[j] * w2[tid * 6 + j];
        scale[tid] = 1.f / (1.f + __expf(-s));
    }
}

// ---------------- bf16 MFMA GEMM: BM=128, BN in {64,128}, BK=32, 4 waves (2x2) ----------
// Grid is (M-blocks, N-blocks): m0 from blockIdx.x so linear_bid%8 == blockIdx.x%8 -> each
// XCD keeps a stable A working set across all N-passes (A re-reads become L2 hits).
// Plain stores: outputs feed the NEXT dispatch (round-4 lesson: nt stores cost +128 us).
template <int MODE, int BN>
__global__ __launch_bounds__(256) void mgemm_k(const unsigned short* __restrict__ A,
                                               const unsigned short* __restrict__ BT,
                                               const float* __restrict__ bias,
                                               const float* __restrict__ xres,
                                               const float* __restrict__ scale,
                                               void* __restrict__ Cout,
                                               int KPd, int N, int cstride, int rowoff) {
    __shared__ unsigned short As[128 * 40];
    __shared__ unsigned short Bs[BN * 40];
    constexpr int NJ = BN / 32;
    const int tid = threadIdx.x;
    const int m0 = blockIdx.x * 128, n0 = blockIdx.y * BN;
    const int arow_l = tid >> 1;
    const int akofs = (tid & 1) * 16;
    size_t arow;
    if (MODE == 3)
        arow = (size_t)win2pix(rowoff + m0 + arow_l) * KPd;
    else
        arow = (size_t)(m0 + arow_l) * KPd;
    const int brow_l = (BN == 128) ? (tid >> 1) : (tid >> 2);
    const int bkofs = (BN == 128) ? ((tid & 1) * 16) : ((tid & 3) * 8);
    const size_t brow = (size_t)(n0 + brow_l) * KPd;
    const int wave = tid >> 6, lane = tid & 63;
    const int wm = (wave & 1) * 64, wn = (wave >> 1) * (BN / 2);
    const int fr = lane & 15, q = lane >> 4;
    floatx4 acc[4][NJ] = {};
    for (int k0 = 0; k0 < KPd; k0 += 32) {
        if (MODE == 5) {
            const unsigned short* Ap = A + ((size_t)(k0 >> 5) * cstride + (m0 + arow_l)) * 32;
            *(float4*)(&As[arow_l * 40 + akofs]) = *(const float4*)(Ap + akofs);
            *(float4*)(&As[arow_l * 40 + akofs + 8]) = *(const float4*)(Ap + akofs + 8);
        } else {
            *(float4*)(&As[arow_l * 40 + akofs]) = *(const float4*)(A + arow + k0 + akofs);
            *(float4*)(&As[arow_l * 40 + akofs + 8]) = *(const float4*)(A + arow + k0 + akofs + 8);
        }
        if (BN == 128) {
            *(float4*)(&Bs[brow_l * 40 + bkofs]) = *(const float4*)(BT + brow + k0 + bkofs);
            *(float4*)(&Bs[brow_l * 40 + bkofs + 8]) = *(const float4*)(BT + brow + k0 + bkofs + 8);
        } else {
            *(float4*)(&Bs[brow_l * 40 + bkofs]) = *(const float4*)(BT + brow + k0 + bkofs);
        }
        __syncthreads();
        bf16x8 af[4], fB[NJ];
#pragma unroll
        for (int i = 0; i < 4; ++i)
            af[i] = *(const bf16x8*)(&As[(wm + i * 16 + fr) * 40 + q * 8]);
#pragma unroll
        for (int j = 0; j < NJ; ++j)
            fB[j] = *(const bf16x8*)(&Bs[(wn + j * 16 + fr) * 40 + q * 8]);
#pragma unroll
        for (int i = 0; i < 4; ++i)
#pragma unroll
            for (int j = 0; j < NJ; ++j)
                acc[i][j] = __builtin_amdgcn_mfma_f32_16x16x32_bf16(af[i], fB[j], acc[i][j], 0, 0, 0);
        __syncthreads();
    }
#pragma unroll
    for (int i = 0; i < 4; ++i) {
#pragma unroll
        for (int r = 0; r < 4; ++r) {
            const int grow = m0 + wm + i * 16 + q * 4 + r;
            int pix = 0;
            if (MODE == 5) pix = win2pix(rowoff + grow);
#pragma unroll
            for (int j = 0; j < NJ; ++j) {
                const int col = n0 + wn + j * 16 + fr;
                float v = acc[i][j][r];
                if (MODE == 1 || MODE == 3) {
                    if (col < cstride) {
                        float vv = 0.f;
                        if (col < N) {
                            vv = v + bias[col];
                            if (MODE == 1) vv = gelu_f(vv);
                        }
                        ((__hip_bfloat16*)Cout)[(size_t)grow * cstride + col] = __float2bfloat16(vv);
                    }
                } else if (MODE == 2) {
                    if (col < N) {
                        float* o = (float*)Cout;
                        size_t ix = (size_t)grow * 180 + col;
                        o[ix] = v + bias[col] + xres[ix];
                    }
                } else if (MODE == 5) {
                    if (col < N) {
                        float* o = (float*)Cout;
                        size_t ix = (size_t)pix * 180 + col;
                        o[ix] = xres[ix] + v + bias[col] + o[ix] * scale[col] * 0.01f;
                    }
                }
            }
        }
    }
}

// ---------------- MFMA flash attention v12 ----------------
// = v9 structure exactly (single rb buffer -> fits the VGPR budget; rounds 2/6/7 proved the
// double-buffer structurally exceeds it and spills) + the exp2 path (rpbM pre-scaled by
// log2e at prep, so exp(x) becomes exp2(fma)) + 32KB swizzled LDS (5 blocks/CU).
__global__ __launch_bounds__(256, 4) void attn12_k(const __hip_bfloat16* __restrict__ qkv,  // [R][576]
                                                   const __hip_bfloat16* __restrict__ rpbM, // [typ][h][qry][key]
                                                   __hip_bfloat16* __restrict__ attn_out,   // [6][rows][32]
                                                   int wbase, int rows) {
    const int wl = blockIdx.x, h = blockIdx.y;
    const int wig = wbase + wl;
    const int typ = (((wig >> 4) == 15) ? 2 : 0) + (((wig & 15) == 15) ? 1 : 0);
    const int tid = threadIdx.x;
    const int w = tid >> 6, lane = tid & 63;
    const int fr = lane & 15, q = lane >> 4;
    // kk: logical [key][d0..31], byte = key*64 + ((slot ^ (key&3))<<4) + inslot, slot=d>>3
    // vT: logical [d][key0..255], byte = d*512 + (((key>>3) ^ d)<<4) + (key&7)*2
    __shared__ __hip_bfloat16 kk[256 * 32];
    __shared__ __hip_bfloat16 vT[32 * 256];

    union UB2 { unsigned int u; __hip_bfloat162 h2; };
    union U8 { unsigned int u[4]; bf16x8 v; };

    // ---- Q fragments (global, independent of LDS) ----
    const int rowbase = wl * 256 + w * 64;
    bf16x8 qf[4];
#pragma unroll
    for (int qi = 0; qi < 4; ++qi) {
        const unsigned int* p32 =
            (const unsigned int*)(qkv + (size_t)(rowbase + qi * 16 + fr) * 576 + h * 30);
        U8 t;
#pragma unroll
        for (int jj = 0; jj < 4; ++jj) t.u[jj] = p32[q * 4 + jj];
        qf[qi] = t.v;
    }

    // ---- rb prefetch for nc=0: issue before staging so L2 latency hides under the drain ----
    const __hip_bfloat16* rpbh = rpbM + ((size_t)(typ * 6 + h)) * 65536;
    uint2 rb[4][4];
#pragma unroll
    for (int qi = 0; qi < 4; ++qi) {
        const size_t qoff = ((size_t)(w * 64 + qi * 16 + fr)) * 256 + q * 4;
#pragma unroll
        for (int ki = 0; ki < 4; ++ki)
            rb[qi][ki] = *(const uint2*)(rpbh + qoff + ki * 16);
    }

    // ---- K/V staging into swizzled LDS ----
    for (int l = tid; l < 256 * 15; l += 256) {
        int key = l / 15, dw_ = l - key * 15;
        const unsigned int* ks =
            (const unsigned int*)(qkv + (size_t)(wl * 256 + key) * 576 + 180 + h * 30);
        unsigned int kv = ks[dw_];
        *(unsigned int*)((char*)kk + key * 64 + (((dw_ >> 2) ^ (key & 3)) << 4) + ((dw_ & 3) << 2)) = kv;
        UB2 vv; vv.u = ks[90 + dw_];
        const int d0 = 2 * dw_, d1 = d0 + 1;
        *(__hip_bfloat16*)((char*)vT + d0 * 512 + (((key >> 3) ^ d0) << 4) + ((key & 7) << 1)) = vv.h2.x;
        *(__hip_bfloat16*)((char*)vT + d1 * 512 + (((key >> 3) ^ d1) << 4) + ((key & 7) << 1)) = vv.h2.y;
    }
    // zero pads: kk d=30,31 (dword 15 of each key row); vT d=30,31 all keys
    *(unsigned int*)((char*)kk + tid * 64 + ((3 ^ (tid & 3)) << 4) + 12) = 0u;
    for (int l = tid; l < 2 * 256; l += 256) {
        int d = 30 + (l >> 8), key = l & 255;
        *(__hip_bfloat16*)((char*)vT + d * 512 + (((key >> 3) ^ d) << 4) + ((key & 7) << 1)) =
            __float2bfloat16(0.f);
    }
    __syncthreads();

    const float SC2 = 0.26339891239045137f;  // (1/sqrt(30)) * log2(e)
    float lsum[4] = {};
    floatx4 o_[4][2] = {};
    const int srcA = fr + ((q & 1) << 5);
    const int srcB = srcA + 16;

#pragma unroll
    for (int nc = 0; nc < 4; ++nc) {
        // rb for this nc (nc=0 already prefetched above)
        if (nc > 0) {
#pragma unroll
            for (int qi = 0; qi < 4; ++qi) {
                const size_t qoff = ((size_t)(w * 64 + qi * 16 + fr)) * 256 + nc * 64 + q * 4;
#pragma unroll
                for (int ki = 0; ki < 4; ++ki)
                    rb[qi][ki] = *(const uint2*)(rpbh + qoff + ki * 16);
            }
        }
        bf16x8 kf[4];
#pragma unroll
        for (int ki = 0; ki < 4; ++ki) {
            const int key = nc * 64 + ki * 16 + fr;
            kf[ki] = *(const bf16x8*)((const char*)kk + key * 64 + ((q ^ (fr & 3)) << 4));
        }
        unsigned int dw[4][4][2];
#pragma unroll
        for (int qi = 0; qi < 4; ++qi) {
            floatx4 s_[4] = {};
#pragma unroll
            for (int ki = 0; ki < 4; ++ki)
                s_[ki] = __builtin_amdgcn_mfma_f32_16x16x32_bf16(kf[ki], qf[qi], s_[ki], 0, 0, 0);
#pragma unroll
            for (int ki = 0; ki < 4; ++ki) {
                uint2 rbv = rb[qi][ki];
                float b0 = bflo(rbv.x), b1 = bfhi(rbv.x), b2 = bflo(rbv.y), b3 = bfhi(rbv.y);
                float p0 = exp2f(fmaf(s_[ki][0], SC2, b0));
                float p1 = exp2f(fmaf(s_[ki][1], SC2, b1));
                float p2 = exp2f(fmaf(s_[ki][2], SC2, b2));
                float p3 = exp2f(fmaf(s_[ki][3], SC2, b3));
                lsum[qi] += (p0 + p1) + (p2 + p3);
                __hip_bfloat162 lo = {__float2bfloat16(p0), __float2bfloat16(p1)};
                __hip_bfloat162 hi = {__float2bfloat16(p2), __float2bfloat16(p3)};
                UB2 ul, uh; ul.h2 = lo; uh.h2 = hi;
                dw[ki][qi][0] = ul.u;
                dw[ki][qi][1] = uh.u;
            }
        }
#pragma unroll
        for (int kc = 0; kc < 2; ++kc) {
            bf16x8 pa[4];
#pragma unroll
            for (int mi = 0; mi < 4; ++mi) {
                unsigned g0 = __shfl((int)dw[2 * kc][mi][0], srcA, 64);
                unsigned g1 = __shfl((int)dw[2 * kc][mi][1], srcA, 64);
                unsigned g2 = __shfl((int)dw[2 * kc][mi][0], srcB, 64);
                unsigned g3 = __shfl((int)dw[2 * kc][mi][1], srcB, 64);
                unsigned h0 = __shfl((int)dw[2 * kc + 1][mi][0], srcA, 64);
                unsigned h1 = __shfl((int)dw[2 * kc + 1][mi][1], srcA, 64);
                unsigned h2 = __shfl((int)dw[2 * kc + 1][mi][0], srcB, 64);
                unsigned h3 = __shfl((int)dw[2 * kc + 1][mi][1], srcB, 64);
                U8 t;
                const bool lo = (q < 2);
                t.u[0] = lo ? g0 : h0;
                t.u[1] = lo ? g1 : h1;
                t.u[2] = lo ? g2 : h2;
                t.u[3] = lo ? g3 : h3;
                pa[mi] = t.v;
            }
            bf16x8 vb[2];
#pragma unroll
            for (int dj = 0; dj < 2; ++dj) {
                const int d = dj * 16 + fr;
                vb[dj] = *(const bf16x8*)((const char*)vT + d * 512 +
                                          (((nc * 8 + kc * 4 + q) ^ d) << 4));
            }
#pragma unroll
            for (int mi = 0; mi < 4; ++mi)
#pragma unroll
                for (int dj = 0; dj < 2; ++dj)
                    o_[mi][dj] =
                        __builtin_amdgcn_mfma_f32_16x16x32_bf16(pa[mi], vb[dj], o_[mi][dj], 0, 0, 0);
        }
    }
    // row sums: reduce across q-groups, redistribute via shfl
#pragma unroll
    for (int qi = 0; qi < 4; ++qi) {
        lsum[qi] += __shfl_xor(lsum[qi], 16, 64);
        lsum[qi] += __shfl_xor(lsum[qi], 32, 64);
    }
    __hip_bfloat16* plane = attn_out + (size_t)h * rows * 32;
#pragma unroll
    for (int mi = 0; mi < 4; ++mi) {
#pragma unroll
        for (int r = 0; r < 4; ++r) {
            float tot = __shfl(lsum[mi], q * 4 + r, 64);
            float inv = 1.f / tot;
            const int row_local = rowbase + mi * 16 + q * 4 + r;
            __hip_bfloat16* orow = plane + (size_t)row_local * 32;
#pragma unroll
            for (int dj = 0; dj < 2; ++dj) {
                int d = dj * 16 + fr;
                float val = (d < 30) ? o_[mi][dj][r] * inv : 0.f;
                orow[d] = __float2bfloat16(val);
            }
        }
    }
}

extern "C" void kernel_launch(void* const* d_in, const int* in_sizes, int n_in, void* d_out,
                              int out_size, void* d_ws, size_t ws_size, hipStream_t stream) {
    (void)in_sizes; (void)n_in; (void)out_size;
    const float* x = (const float*)d_in[0];
    const int* rpi = (const int*)d_in[3];
    const float* mask = (const float*)d_in[4];
    const float* n1g = (const float*)d_in[5];
    const float* n1b = (const float*)d_in[6];
    const float* qkvw = (const float*)d_in[7];
    const float* qkvb = (const float*)d_in[8];
    const float* rpbt = (const float*)d_in[9];
    const float* projw = (const float*)d_in[10];
    const float* projb = (const float*)d_in[11];
    const float* c1w = (const float*)d_in[12];
    const float* c1b = (const float*)d_in[13];
    const float* c2w = (const float*)d_in[14];
    const float* c2b = (const float*)d_in[15];
    const float* ca1w = (const float*)d_in[16];
    const float* ca1b = (const float*)d_in[17];
    const float* ca2w = (const float*)d_in[18];
    const float* ca2b = (const float*)d_in[19];
    const float* n2g = (const float*)d_in[20];
    const float* n2b = (const float*)d_in[21];
    const float* f1w = (const float*)d_in[22];
    const float* f1b = (const float*)d_in[23];
    const float* f2w = (const float*)d_in[24];
    const float* f2b = (const float*)d_in[25];

    float* ws = (float*)d_ws;
    float* out = (float*)d_out;  // y2 -> x2 -> final output (in place, disjoint phases)

    // Merged attention path needs 130,511,616 B of workspace; fall back to 2-chunk if smaller.
    const int merged = (ws_size >= 130511616ull) ? 1 : 0;
    const int RATT = merged ? 65536 : 32768;
    const int nck = merged ? 1 : 2;
    const size_t bufCf = merged ? 25165824u : 12582912u;   // floats in the big shared region
    const size_t attnCoff = merged ? 18874368u : 9437184u; // float offset of attnC inside bufC

    // workspace layout (floats; offsets 16B-aligned)
    float* xn_f     = ws;                    // 6,291,456 (65536x192 bf16)
    float* bufC     = xn_f + 6291456;        // y1b | qkvC+attnC | h1 (all bf16)
    float* partials = bufC + bufCf;          // 46,080
    float* scalep   = partials + 46080;      // 192
    float* rpbM_f   = scalep + 192;          // 786,432 (4x6x65536 bf16, rpb+mask fused)
    float* wb1_f    = rpbM_f + 786432;       // 55,296
    float* wb2_f    = wb1_f + 55296;         // 55,296
    float* qkvbt_f  = wb2_f + 55296;         // 61,440  (640x192 bf16)
    float* projbt_f = qkvbt_f + 61440;       // 18,432  (192x192 bf16)
    float* f1bt_f   = projbt_f + 18432;      // 73,728  (768x192 bf16)
    float* f2bt_f   = f1bt_f + 73728;        // 73,728  (192x768 bf16)

    __hip_bfloat16* xn    = (__hip_bfloat16*)xn_f;
    __hip_bfloat16* y1b   = (__hip_bfloat16*)bufC;                  // 65536x64
    __hip_bfloat16* qkvC  = (__hip_bfloat16*)bufC;                  // RATTx576
    __hip_bfloat16* attnC = (__hip_bfloat16*)(bufC + attnCoff);     // 6xRATTx32 planar
    __hip_bfloat16* h1    = (__hip_bfloat16*)bufC;                  // (merged: 65536, else 32768)x768
    __hip_bfloat16* rpbM   = (__hip_bfloat16*)rpbM_f;
    __hip_bfloat16* wb1    = (__hip_bfloat16*)wb1_f;
    __hip_bfloat16* wb2    = (__hip_bfloat16*)wb2_f;
    __hip_bfloat16* qkvbt  = (__hip_bfloat16*)qkvbt_f;
    __hip_bfloat16* projbt = (__hip_bfloat16*)projbt_f;
    __hip_bfloat16* f1bt   = (__hip_bfloat16*)f1bt_f;
    __hip_bfloat16* f2bt   = (__hip_bfloat16*)f2bt_f;

    // ---- fused prep (741,376 items) ----
    prep_all_k<<<(741376 + 255) / 256, 256, 0, stream>>>(rpi, rpbt, mask, rpbM, c1w, wb1, c2w, wb2,
                                                         qkvw, qkvbt, projw, projbt,
                                                         f1w, f1bt, f2w, f2bt);

    // ---- LN1 -> bf16 ----
    ln_k<<<NTOK / 4, 256, 0, stream>>>(x, n1g, n1b, xn);

    // ---- CAB conv branch (MFMA): y2 lives in d_out ----
    mconv_k<8, 192, 60, 64, 1, 1><<<dim3(512, 1), 256, 0, stream>>>(xn, 192, wb1, c1b, y1b);
    mconv_k<16, 64, 180, 180, 0, 0><<<dim3(256, 3), 256, 0, stream>>>(y1b, 64, wb2, c2b, out);
    chansum_k<<<256, 192, 0, stream>>>(out, partials);
    ca_k<<<1, 256, 0, stream>>>(partials, ca1w, ca1b, ca2w, ca2b, scalep);

    // ---- attention branch (merged: 1 chunk of 256 windows; fallback: 2x128) ----
    for (int ck = 0; ck < nck; ++ck) {
        const int rowoff = ck * RATT;
        mgemm_k<3, 128><<<dim3(RATT / 128, 5), 256, 0, stream>>>(
            (const unsigned short*)xn, (const unsigned short*)qkvbt, qkvb, nullptr, nullptr,
            qkvC, 192, 540, 576, rowoff);
        attn12_k<<<dim3(RATT / 256, 6), 256, 0, stream>>>(qkvC, rpbM, attnC, rowoff / 256, RATT);
        mgemm_k<5, 64><<<dim3(RATT / 128, 3), 256, 0, stream>>>(
            (const unsigned short*)attnC, (const unsigned short*)projbt, projb, x, scalep,
            out, 192, 180, RATT, rowoff);
    }

    // ---- LN2 (x2 in d_out) -> bf16 xm ----
    ln_k<<<NTOK / 4, 256, 0, stream>>>(out, n2g, n2b, xn);

    // ---- MLP (merged: single pass over all 65536 rows; h1 fits bufC exactly) ----
    const int nmlp = merged ? 1 : 2;
    const int RM = merged ? NTOK : RCHUNK;
    for (int ck = 0; ck < nmlp; ++ck) {
        const int rowoff = ck * RM;
        mgemm_k<1, 128><<<dim3(RM / 128, 6), 256, 0, stream>>>(
            (const unsigned short*)(xn + (size_t)rowoff * KP1), (const unsigned short*)f1bt,
            f1b, nullptr, nullptr, h1, 192, 720, 768, 0);
        mgemm_k<2, 64><<<dim3(RM / 128, 3), 256, 0, stream>>>(
            (const unsigned short*)h1, (const unsigned short*)f2bt, f2b,
            out + (size_t)rowoff * 180, nullptr, out + (size_t)rowoff * 180, 768, 180, 180, 0);
    }
}

// Round 9
// 623.964 us; speedup vs baseline: 1.2001x; 1.0006x over previous
//
#include <hip/hip_runtime.h>
#include <hip/hip_bf16.h>
#include <math.h>

#define NTOK 65536
#define C 180
#define KP1 192      // padded K for C=180
#define RCHUNK 32768 // rows per chunk (128 windows) for the MLP fallback
#define LOG2E 1.4426950408889634f

typedef __attribute__((ext_vector_type(8))) __bf16 bf16x8;
typedef __attribute__((ext_vector_type(4))) float floatx4;

__device__ __forceinline__ float gelu_f(float v) {
    return 0.5f * v * (1.f + erff(v * 0.7071067811865475f));
}
__device__ __forceinline__ float bflo(unsigned int u) { return __uint_as_float(u << 16); }
__device__ __forceinline__ float bfhi(unsigned int u) { return __uint_as_float(u & 0xffff0000u); }

// async global->LDS DMA, 16B per lane; lds dest must be wave-uniform base (lane x 16 implicit)
__device__ __forceinline__ void async_copy16(const unsigned short* g, unsigned short* l) {
    __builtin_amdgcn_global_load_lds(
        (const __attribute__((address_space(1))) unsigned int*)g,
        (__attribute__((address_space(3))) unsigned int*)l, 16, 0, 0);
}

// window-row (shifted-window order) -> pixel row index in [0, 65536)
__device__ __forceinline__ int win2pix(int wrow) {
    int wi = wrow >> 8, ni = wrow & 255;
    int r2 = ((wi >> 4) << 4) | (ni >> 4);
    int c2 = ((wi & 15) << 4) | (ni & 15);
    int r = (r2 + 8) & 255, c = (c2 + 8) & 255;
    return (r << 8) | c;
}

// ---------------- LayerNorm: fp32 in (stride 180) -> bf16 out (stride 192, zero pad) -----------
__global__ __launch_bounds__(256) void ln_k(const float* __restrict__ x,
                                            const float* __restrict__ g,
                                            const float* __restrict__ b,
                                            __hip_bfloat16* __restrict__ y) {
    const int wav = threadIdx.x >> 6;
    const int lane = threadIdx.x & 63;
    const int row = blockIdx.x * 4 + wav;
    const float* xr = x + (size_t)row * C;
    float v0 = xr[lane];
    float v1 = xr[lane + 64];
    float v2 = (lane < C - 128) ? xr[lane + 128] : 0.f;
    float sum = v0 + v1 + v2;
    float sq = v0 * v0 + v1 * v1 + v2 * v2;
#pragma unroll
    for (int off = 32; off >= 1; off >>= 1) {
        sum += __shfl_xor(sum, off, 64);
        sq += __shfl_xor(sq, off, 64);
    }
    const float mu = sum * (1.f / C);
    const float var = sq * (1.f / C) - mu * mu;
    const float rstd = rsqrtf(var + 1e-5f);
    __hip_bfloat16* yr = y + (size_t)row * KP1;
#pragma unroll
    for (int e = 0; e < 3; ++e) {
        int col = lane + 64 * e;
        float val = 0.f;
        if (col < C) {
            float vv = (e == 0) ? v0 : (e == 1 ? v1 : v2);
            val = (vv - mu) * rstd * g[col] + b[col];
        }
        yr[col] = __float2bfloat16(val);
    }
}

// ---------------- fused weight/bias prep (one dispatch) ----------------
__device__ __forceinline__ void wconv_item(const float* __restrict__ w,
                                           __hip_bfloat16* __restrict__ wb,
                                           int O, int I, int OCP, int KP, int idx) {
    int tap = idx / (OCP * KP);
    int rem = idx - tap * (OCP * KP);
    int oc = rem / KP, ch = rem - oc * KP;
    float v = (oc < O && ch < I) ? w[((size_t)(oc * I + ch)) * 9 + tap] : 0.f;
    wb[idx] = __float2bfloat16(v);
}
__device__ __forceinline__ void wprep_item(const float* __restrict__ w,
                                           __hip_bfloat16* __restrict__ bt,
                                           int K, int N, int KPd, int idx) {
    int n = idx / KPd, k = idx - n * KPd;
    float v = (n < N && k < K) ? w[(size_t)k * N + n] : 0.f;
    bt[idx] = __float2bfloat16(v);
}
// ranges: [0,65536) rpbM (4 types x 6 heads fused rpb+mask, pre-scaled by log2e for exp2) |
//         +110592 wconv1 | +110592 wconv2 | +122880 qkv | +36864 proj | +147456 f1 |
//         +147456 f2   total 741,376
__global__ void prep_all_k(const int* __restrict__ rpi, const float* __restrict__ table,
                           const float* __restrict__ mask,
                           __hip_bfloat16* __restrict__ rpbM,
                           const float* __restrict__ c1w, __hip_bfloat16* __restrict__ wb1,
                           const float* __restrict__ c2w, __hip_bfloat16* __restrict__ wb2,
                           const float* __restrict__ qkvw, __hip_bfloat16* __restrict__ qkvbt,
                           const float* __restrict__ projw, __hip_bfloat16* __restrict__ projbt,
                           const float* __restrict__ f1w, __hip_bfloat16* __restrict__ f1bt,
                           const float* __restrict__ f2w, __hip_bfloat16* __restrict__ f2bt) {
    int idx = blockIdx.x * 256 + threadIdx.x;
    if (idx < 65536) {
        int t = rpi[idx];
        // 4 distinct shifted-window mask patterns: interior / right col / bottom row / corner.
        float m1 = mask[(size_t)15 * 65536 + idx];
        float m2 = mask[(size_t)240 * 65536 + idx];
        float m3 = mask[(size_t)255 * 65536 + idx];
#pragma unroll
        for (int h = 0; h < 6; ++h) {
            float base = table[t * 6 + h];
            rpbM[((size_t)(0 * 6 + h)) * 65536 + idx] = __float2bfloat16(base * LOG2E);
            rpbM[((size_t)(1 * 6 + h)) * 65536 + idx] = __float2bfloat16((base + m1) * LOG2E);
            rpbM[((size_t)(2 * 6 + h)) * 65536 + idx] = __float2bfloat16((base + m2) * LOG2E);
            rpbM[((size_t)(3 * 6 + h)) * 65536 + idx] = __float2bfloat16((base + m3) * LOG2E);
        }
        return;
    }
    idx -= 65536;
    if (idx < 110592) { wconv_item(c1w, wb1, 60, 180, 64, 192, idx); return; }
    idx -= 110592;
    if (idx < 110592) { wconv_item(c2w, wb2, 180, 60, 192, 64, idx); return; }
    idx -= 110592;
    if (idx < 122880) { wprep_item(qkvw, qkvbt, 180, 540, 192, idx); return; }
    idx -= 122880;
    if (idx < 36864) { wprep_item(projw, projbt, 180, 180, 192, idx); return; }
    idx -= 36864;
    if (idx < 147456) { wprep_item(f1w, f1bt, 180, 720, 192, idx); return; }
    idx -= 147456;
    if (idx < 147456) { wprep_item(f2w, f2bt, 720, 180, 768, idx); return; }
}

// ---------------- MFMA implicit-GEMM conv 3x3, NHWC bf16 in, pad 1 ----------------
template <int TH, int CINP, int COUT, int OSTR, int ACT, int OUTBF>
__global__ __launch_bounds__(256) void mconv_k(const __hip_bfloat16* __restrict__ in, int istr,
                                               const __hip_bfloat16* __restrict__ wb,
                                               const float* __restrict__ bias,
                                               void* __restrict__ outp) {
    constexpr int MI = TH / 4;
    __shared__ __hip_bfloat16 sP[(TH + 2) * 18 * 40];
    __shared__ __hip_bfloat16 sW[9 * 64 * 40];
    const int tid = threadIdx.x;
    const int tr0 = (blockIdx.x >> 4) * TH, tc0 = (blockIdx.x & 15) * 16;
    const int ocbase = blockIdx.y * 64;
    const int w = tid >> 6, lane = tid & 63, fr = lane & 15, q = lane >> 4;
    constexpr int OCP = ((COUT + 63) / 64) * 64;
    floatx4 acc[MI][4] = {};
    for (int c0 = 0; c0 < CINP; c0 += 32) {
        for (int l = tid; l < (TH + 2) * 18 * 4; l += 256) {
            int pos = l >> 2, part = l & 3;
            int pr = pos / 18, pc = pos - pr * 18;
            int gr = tr0 + pr - 1, gc = tc0 + pc - 1;
            float4 v = make_float4(0.f, 0.f, 0.f, 0.f);
            if (gr >= 0 && gr < 256 && gc >= 0 && gc < 256)
                v = *(const float4*)(in + (size_t)(gr * 256 + gc) * istr + c0 + part * 8);
            *(float4*)(sP + pos * 40 + part * 8) = v;
        }
        for (int l = tid; l < 9 * 64 * 4; l += 256) {
            int part = l & 3, oc = (l >> 2) & 63, tap = l >> 8;
            *(float4*)(sW + tap * 2560 + oc * 40 + part * 8) =
                *(const float4*)(wb + (size_t)(tap * OCP + ocbase + oc) * CINP + c0 + part * 8);
        }
        __syncthreads();
#pragma unroll
        for (int tap = 0; tap < 9; ++tap) {
            const int dy = tap / 3, dx = tap - 3 * (tap / 3);
            bf16x8 af[MI], bw[4];
#pragma unroll
            for (int mi = 0; mi < MI; ++mi) {
                int pr = MI * w + mi + dy, pc = fr + dx;
                af[mi] = *(const bf16x8*)(sP + (pr * 18 + pc) * 40 + q * 8);
            }
#pragma unroll
            for (int nj = 0; nj < 4; ++nj)
                bw[nj] = *(const bf16x8*)(sW + tap * 2560 + (nj * 16 + fr) * 40 + q * 8);
#pragma unroll
            for (int mi = 0; mi < MI; ++mi)
#pragma unroll
                for (int nj = 0; nj < 4; ++nj)
                    acc[mi][nj] =
                        __builtin_amdgcn_mfma_f32_16x16x32_bf16(af[mi], bw[nj], acc[mi][nj], 0, 0, 0);
        }
        __syncthreads();
    }
#pragma unroll
    for (int mi = 0; mi < MI; ++mi) {
#pragma unroll
        for (int r = 0; r < 4; ++r) {
            const int irow = tr0 + MI * w + mi;
            const int icol = tc0 + q * 4 + r;
            const size_t obase = (size_t)(irow * 256 + icol) * OSTR + ocbase;
#pragma unroll
            for (int nj = 0; nj < 4; ++nj) {
                int oc = ocbase + nj * 16 + fr;
                float bv = (oc < COUT) ? bias[oc] : 0.f;
                float v = acc[mi][nj][r] + bv;
                if (ACT) v = gelu_f(v);
                if (OUTBF) {
                    ((__hip_bfloat16*)outp)[obase + nj * 16 + fr] = __float2bfloat16(v);
                } else {
                    if (oc < COUT) ((float*)outp)[obase + nj * 16 + fr] = v;
                }
            }
        }
    }
}

// ---------------- channel sums ----------------
__global__ __launch_bounds__(192) void chansum_k(const float* __restrict__ y2,
                                                 float* __restrict__ partials) {
    const int tid = threadIdx.x;
    if (tid >= C) return;
    const size_t base = (size_t)blockIdx.x * 256 * C;
    float s = 0.f;
    for (int p = 0; p < 256; ++p) s += y2[base + (size_t)p * C + tid];
    partials[blockIdx.x * C + tid] = s;
}

// ---------------- channel attention MLP (1 block) ----------------
__global__ __launch_bounds__(256) void ca_k(const float* __restrict__ partials,
                                            const float* __restrict__ w1, const float* __restrict__ b1,
                                            const float* __restrict__ w2, const float* __restrict__ b2,
                                            float* __restrict__ scale) {
    __shared__ float mean[C];
    __shared__ float s1[6];
    const int tid = threadIdx.x;
    if (tid < C) {
        float s = 0.f;
        for (int b_ = 0; b_ < 256; ++b_) s += partials[b_ * C + tid];
        mean[tid] = s * (1.f / 65536.f);
    }
    __syncthreads();
    if (tid < 6) {
        float s = b1[tid];
        for (int ch = 0; ch < C; ++ch) s += mean[ch] * w1[tid * C + ch];
        s1[tid] = fmaxf(s, 0.f);
    }
    __syncthreads();
    if (tid < C) {
        float s = b2[tid];
#pragma unroll
        for (int j = 0; j < 6; ++j) s += s1[j] * w2[tid * 6 + j];
        scale[tid] = 1.f / (1.f + __expf(-s));
    }
}

// ---------------- bf16 MFMA GEMM v2: BM=128, BN in {64,128}, BK=32, 4 waves (2x2) ----------
// Staging via __builtin_amdgcn_global_load_lds (16B/lane async DMA, no VGPR round-trip).
// LDS tiles are unpadded [row][32] with the attn-kk XOR swizzle: slot = chunk ^ (row&3)
// (16B slots). DMA writes linearly (wave base + lane*16), so the swizzle is applied on the
// per-lane GLOBAL source address; fragment reads apply the same XOR (rule #21: linear dest +
// inverse-swz source + swz read). __syncthreads drains vmcnt -> DMA completion guaranteed.
// Grid (M,N) transposed for per-XCD A reuse; plain stores (round-4 lesson).
template <int MODE, int BN>
__global__ __launch_bounds__(256) void mgemm_k(const unsigned short* __restrict__ A,
                                               const unsigned short* __restrict__ BT,
                                               const float* __restrict__ bias,
                                               const float* __restrict__ xres,
                                               const float* __restrict__ scale,
                                               void* __restrict__ Cout,
                                               int KPd, int N, int cstride, int rowoff) {
    __shared__ unsigned short As[128 * 32];
    __shared__ unsigned short Bs[BN * 32];
    constexpr int NJ = BN / 32;
    const int tid = threadIdx.x;
    const int m0 = blockIdx.x * 128, n0 = blockIdx.y * BN;
    const int wave = tid >> 6, lane = tid & 63;
    const int wm = (wave & 1) * 64, wn = (wave >> 1) * (BN / 2);
    const int fr = lane & 15, q = lane >> 4;
    const int subrow = lane >> 2;                    // 0..15 within a 16-row segment
    const int chunk = (lane & 3) ^ (subrow & 3);     // pre-swizzled global chunk

    // per-segment row bases (named scalars -> no runtime-indexed arrays, rule #20)
    const int rl0 = wave * 16 + subrow;              // segment wave   (c=0)
    const int rl1 = (wave + 4) * 16 + subrow;        // segment wave+4 (c=1)
    size_t abase0, abase1;
    if (MODE == 3) {
        abase0 = (size_t)win2pix(rowoff + m0 + rl0) * KPd + chunk * 8;
        abase1 = (size_t)win2pix(rowoff + m0 + rl1) * KPd + chunk * 8;
    } else if (MODE == 5) {
        abase0 = (size_t)(m0 + rl0) * 32 + chunk * 8;
        abase1 = (size_t)(m0 + rl1) * 32 + chunk * 8;
    } else {
        abase0 = (size_t)(m0 + rl0) * KPd + chunk * 8;
        abase1 = (size_t)(m0 + rl1) * KPd + chunk * 8;
    }
    const size_t bbase0 = (size_t)(n0 + rl0) * KPd + chunk * 8;
    const size_t bbase1 = (size_t)(n0 + rl1) * KPd + chunk * 8;

    floatx4 acc[4][NJ] = {};
    for (int k0 = 0; k0 < KPd; k0 += 32) {
        // A: 8 segments of 1KB (rows seg*16..+16, 4 chunks/row)
        if (MODE == 5) {
            const size_t kofs = (size_t)(k0 >> 5) * cstride * 32;
            async_copy16(A + kofs + abase0, As + wave * 512);
            async_copy16(A + kofs + abase1, As + (wave + 4) * 512);
        } else {
            async_copy16(A + abase0 + k0, As + wave * 512);
            async_copy16(A + abase1 + k0, As + (wave + 4) * 512);
        }
        // B: BN/16 segments
        async_copy16(BT + bbase0 + k0, Bs + wave * 512);
        if (BN == 128) async_copy16(BT + bbase1 + k0, Bs + (wave + 4) * 512);
        __syncthreads();  // drains vmcnt -> DMA landed
        bf16x8 af[4], fB[NJ];
        const int sw = (q ^ (fr & 3)) << 4;
#pragma unroll
        for (int i = 0; i < 4; ++i)
            af[i] = *(const bf16x8*)((const char*)As + (wm + i * 16 + fr) * 64 + sw);
#pragma unroll
        for (int j = 0; j < NJ; ++j)
            fB[j] = *(const bf16x8*)((const char*)Bs + (wn + j * 16 + fr) * 64 + sw);
#pragma unroll
        for (int i = 0; i < 4; ++i)
#pragma unroll
            for (int j = 0; j < NJ; ++j)
                acc[i][j] = __builtin_amdgcn_mfma_f32_16x16x32_bf16(af[i], fB[j], acc[i][j], 0, 0, 0);
        __syncthreads();
    }
#pragma unroll
    for (int i = 0; i < 4; ++i) {
#pragma unroll
        for (int r = 0; r < 4; ++r) {
            const int grow = m0 + wm + i * 16 + q * 4 + r;
            int pix = 0;
            if (MODE == 5) pix = win2pix(rowoff + grow);
#pragma unroll
            for (int j = 0; j < NJ; ++j) {
                const int col = n0 + wn + j * 16 + fr;
                float v = acc[i][j][r];
                if (MODE == 1 || MODE == 3) {
                    if (col < cstride) {
                        float vv = 0.f;
                        if (col < N) {
                            vv = v + bias[col];
                            if (MODE == 1) vv = gelu_f(vv);
                        }
                        ((__hip_bfloat16*)Cout)[(size_t)grow * cstride + col] = __float2bfloat16(vv);
                    }
                } else if (MODE == 2) {
                    if (col < N) {
                        float* o = (float*)Cout;
                        size_t ix = (size_t)grow * 180 + col;
                        o[ix] = v + bias[col] + xres[ix];
                    }
                } else if (MODE == 5) {
                    if (col < N) {
                        float* o = (float*)Cout;
                        size_t ix = (size_t)pix * 180 + col;
                        o[ix] = xres[ix] + v + bias[col] + o[ix] * scale[col] * 0.01f;
                    }
                }
            }
        }
    }
}

// ---------------- MFMA flash attention v12 (unchanged from round 8) ----------------
__global__ __launch_bounds__(256, 4) void attn12_k(const __hip_bfloat16* __restrict__ qkv,  // [R][576]
                                                   const __hip_bfloat16* __restrict__ rpbM, // [typ][h][qry][key]
                                                   __hip_bfloat16* __restrict__ attn_out,   // [6][rows][32]
                                                   int wbase, int rows) {
    const int wl = blockIdx.x, h = blockIdx.y;
    const int wig = wbase + wl;
    const int typ = (((wig >> 4) == 15) ? 2 : 0) + (((wig & 15) == 15) ? 1 : 0);
    const int tid = threadIdx.x;
    const int w = tid >> 6, lane = tid & 63;
    const int fr = lane & 15, q = lane >> 4;
    // kk: logical [key][d0..31], byte = key*64 + ((slot ^ (key&3))<<4) + inslot, slot=d>>3
    // vT: logical [d][key0..255], byte = d*512 + (((key>>3) ^ d)<<4) + (key&7)*2
    __shared__ __hip_bfloat16 kk[256 * 32];
    __shared__ __hip_bfloat16 vT[32 * 256];

    union UB2 { unsigned int u; __hip_bfloat162 h2; };
    union U8 { unsigned int u[4]; bf16x8 v; };

    // ---- Q fragments (global, independent of LDS) ----
    const int rowbase = wl * 256 + w * 64;
    bf16x8 qf[4];
#pragma unroll
    for (int qi = 0; qi < 4; ++qi) {
        const unsigned int* p32 =
            (const unsigned int*)(qkv + (size_t)(rowbase + qi * 16 + fr) * 576 + h * 30);
        U8 t;
#pragma unroll
        for (int jj = 0; jj < 4; ++jj) t.u[jj] = p32[q * 4 + jj];
        qf[qi] = t.v;
    }

    // ---- rb prefetch for nc=0: issue before staging so L2 latency hides under the drain ----
    const __hip_bfloat16* rpbh = rpbM + ((size_t)(typ * 6 + h)) * 65536;
    uint2 rb[4][4];
#pragma unroll
    for (int qi = 0; qi < 4; ++qi) {
        const size_t qoff = ((size_t)(w * 64 + qi * 16 + fr)) * 256 + q * 4;
#pragma unroll
        for (int ki = 0; ki < 4; ++ki)
            rb[qi][ki] = *(const uint2*)(rpbh + qoff + ki * 16);
    }

    // ---- K/V staging into swizzled LDS ----
    for (int l = tid; l < 256 * 15; l += 256) {
        int key = l / 15, dw_ = l - key * 15;
        const unsigned int* ks =
            (const unsigned int*)(qkv + (size_t)(wl * 256 + key) * 576 + 180 + h * 30);
        unsigned int kv = ks[dw_];
        *(unsigned int*)((char*)kk + key * 64 + (((dw_ >> 2) ^ (key & 3)) << 4) + ((dw_ & 3) << 2)) = kv;
        UB2 vv; vv.u = ks[90 + dw_];
        const int d0 = 2 * dw_, d1 = d0 + 1;
        *(__hip_bfloat16*)((char*)vT + d0 * 512 + (((key >> 3) ^ d0) << 4) + ((key & 7) << 1)) = vv.h2.x;
        *(__hip_bfloat16*)((char*)vT + d1 * 512 + (((key >> 3) ^ d1) << 4) + ((key & 7) << 1)) = vv.h2.y;
    }
    // zero pads: kk d=30,31 (dword 15 of each key row); vT d=30,31 all keys
    *(unsigned int*)((char*)kk + tid * 64 + ((3 ^ (tid & 3)) << 4) + 12) = 0u;
    for (int l = tid; l < 2 * 256; l += 256) {
        int d = 30 + (l >> 8), key = l & 255;
        *(__hip_bfloat16*)((char*)vT + d * 512 + (((key >> 3) ^ d) << 4) + ((key & 7) << 1)) =
            __float2bfloat16(0.f);
    }
    __syncthreads();

    const float SC2 = 0.26339891239045137f;  // (1/sqrt(30)) * log2(e)
    float lsum[4] = {};
    floatx4 o_[4][2] = {};
    const int srcA = fr + ((q & 1) << 5);
    const int srcB = srcA + 16;

#pragma unroll
    for (int nc = 0; nc < 4; ++nc) {
        // rb for this nc (nc=0 already prefetched above)
        if (nc > 0) {
#pragma unroll
            for (int qi = 0; qi < 4; ++qi) {
                const size_t qoff = ((size_t)(w * 64 + qi * 16 + fr)) * 256 + nc * 64 + q * 4;
#pragma unroll
                for (int ki = 0; ki < 4; ++ki)
                    rb[qi][ki] = *(const uint2*)(rpbh + qoff + ki * 16);
            }
        }
        bf16x8 kf[4];
#pragma unroll
        for (int ki = 0; ki < 4; ++ki) {
            const int key = nc * 64 + ki * 16 + fr;
            kf[ki] = *(const bf16x8*)((const char*)kk + key * 64 + ((q ^ (fr & 3)) << 4));
        }
        unsigned int dw[4][4][2];
#pragma unroll
        for (int qi = 0; qi < 4; ++qi) {
            floatx4 s_[4] = {};
#pragma unroll
            for (int ki = 0; ki < 4; ++ki)
                s_[ki] = __builtin_amdgcn_mfma_f32_16x16x32_bf16(kf[ki], qf[qi], s_[ki], 0, 0, 0);
#pragma unroll
            for (int ki = 0; ki < 4; ++ki) {
                uint2 rbv = rb[qi][ki];
                float b0 = bflo(rbv.x), b1 = bfhi(rbv.x), b2 = bflo(rbv.y), b3 = bfhi(rbv.y);
                float p0 = exp2f(fmaf(s_[ki][0], SC2, b0));
                float p1 = exp2f(fmaf(s_[ki][1], SC2, b1));
                float p2 = exp2f(fmaf(s_[ki][2], SC2, b2));
                float p3 = exp2f(fmaf(s_[ki][3], SC2, b3));
                lsum[qi] += (p0 + p1) + (p2 + p3);
                __hip_bfloat162 lo = {__float2bfloat16(p0), __float2bfloat16(p1)};
                __hip_bfloat162 hi = {__float2bfloat16(p2), __float2bfloat16(p3)};
                UB2 ul, uh; ul.h2 = lo; uh.h2 = hi;
                dw[ki][qi][0] = ul.u;
                dw[ki][qi][1] = uh.u;
            }
        }
#pragma unroll
        for (int kc = 0; kc < 2; ++kc) {
            bf16x8 pa[4];
#pragma unroll
            for (int mi = 0; mi < 4; ++mi) {
                unsigned g0 = __shfl((int)dw[2 * kc][mi][0], srcA, 64);
                unsigned g1 = __shfl((int)dw[2 * kc][mi][1], srcA, 64);
                unsigned g2 = __shfl((int)dw[2 * kc][mi][0], srcB, 64);
                unsigned g3 = __shfl((int)dw[2 * kc][mi][1], srcB, 64);
                unsigned h0 = __shfl((int)dw[2 * kc + 1][mi][0], srcA, 64);
                unsigned h1 = __shfl((int)dw[2 * kc + 1][mi][1], srcA, 64);
                unsigned h2 = __shfl((int)dw[2 * kc + 1][mi][0], srcB, 64);
                unsigned h3 = __shfl((int)dw[2 * kc + 1][mi][1], srcB, 64);
                U8 t;
                const bool lo = (q < 2);
                t.u[0] = lo ? g0 : h0;
                t.u[1] = lo ? g1 : h1;
                t.u[2] = lo ? g2 : h2;
                t.u[3] = lo ? g3 : h3;
                pa[mi] = t.v;
            }
            bf16x8 vb[2];
#pragma unroll
            for (int dj = 0; dj < 2; ++dj) {
                const int d = dj * 16 + fr;
                vb[dj] = *(const bf16x8*)((const char*)vT + d * 512 +
                                          (((nc * 8 + kc * 4 + q) ^ d) << 4));
            }
#pragma unroll
            for (int mi = 0; mi < 4; ++mi)
#pragma unroll
                for (int dj = 0; dj < 2; ++dj)
                    o_[mi][dj] =
                        __builtin_amdgcn_mfma_f32_16x16x32_bf16(pa[mi], vb[dj], o_[mi][dj], 0, 0, 0);
        }
    }
    // row sums: reduce across q-groups, redistribute via shfl
#pragma unroll
    for (int qi = 0; qi < 4; ++qi) {
        lsum[qi] += __shfl_xor(lsum[qi], 16, 64);
        lsum[qi] += __shfl_xor(lsum[qi], 32, 64);
    }
    __hip_bfloat16* plane = attn_out + (size_t)h * rows * 32;
#pragma unroll
    for (int mi = 0; mi < 4; ++mi) {
#pragma unroll
        for (int r = 0; r < 4; ++r) {
            float tot = __shfl(lsum[mi], q * 4 + r, 64);
            float inv = 1.f / tot;
            const int row_local = rowbase + mi * 16 + q * 4 + r;
            __hip_bfloat16* orow = plane + (size_t)row_local * 32;
#pragma unroll
            for (int dj = 0; dj < 2; ++dj) {
                int d = dj * 16 + fr;
                float val = (d < 30) ? o_[mi][dj][r] * inv : 0.f;
                orow[d] = __float2bfloat16(val);
            }
        }
    }
}

extern "C" void kernel_launch(void* const* d_in, const int* in_sizes, int n_in, void* d_out,
                              int out_size, void* d_ws, size_t ws_size, hipStream_t stream) {
    (void)in_sizes; (void)n_in; (void)out_size;
    const float* x = (const float*)d_in[0];
    const int* rpi = (const int*)d_in[3];
    const float* mask = (const float*)d_in[4];
    const float* n1g = (const float*)d_in[5];
    const float* n1b = (const float*)d_in[6];
    const float* qkvw = (const float*)d_in[7];
    const float* qkvb = (const float*)d_in[8];
    const float* rpbt = (const float*)d_in[9];
    const float* projw = (const float*)d_in[10];
    const float* projb = (const float*)d_in[11];
    const float* c1w = (const float*)d_in[12];
    const float* c1b = (const float*)d_in[13];
    const float* c2w = (const float*)d_in[14];
    const float* c2b = (const float*)d_in[15];
    const float* ca1w = (const float*)d_in[16];
    const float* ca1b = (const float*)d_in[17];
    const float* ca2w = (const float*)d_in[18];
    const float* ca2b = (const float*)d_in[19];
    const float* n2g = (const float*)d_in[20];
    const float* n2b = (const float*)d_in[21];
    const float* f1w = (const float*)d_in[22];
    const float* f1b = (const float*)d_in[23];
    const float* f2w = (const float*)d_in[24];
    const float* f2b = (const float*)d_in[25];

    float* ws = (float*)d_ws;
    float* out = (float*)d_out;  // y2 -> x2 -> final output (in place, disjoint phases)

    // Merged attention path needs 130,511,616 B of workspace; fall back to 2-chunk if smaller.
    const int merged = (ws_size >= 130511616ull) ? 1 : 0;
    const int RATT = merged ? 65536 : 32768;
    const int nck = merged ? 1 : 2;
    const size_t bufCf = merged ? 25165824u : 12582912u;   // floats in the big shared region
    const size_t attnCoff = merged ? 18874368u : 9437184u; // float offset of attnC inside bufC

    // workspace layout (floats; offsets 16B-aligned)
    float* xn_f     = ws;                    // 6,291,456 (65536x192 bf16)
    float* bufC     = xn_f + 6291456;        // y1b | qkvC+attnC | h1 (all bf16)
    float* partials = bufC + bufCf;          // 46,080
    float* scalep   = partials + 46080;      // 192
    float* rpbM_f   = scalep + 192;          // 786,432 (4x6x65536 bf16, rpb+mask fused)
    float* wb1_f    = rpbM_f + 786432;       // 55,296
    float* wb2_f    = wb1_f + 55296;         // 55,296
    float* qkvbt_f  = wb2_f + 55296;         // 61,440  (640x192 bf16)
    float* projbt_f = qkvbt_f + 61440;       // 18,432  (192x192 bf16)
    float* f1bt_f   = projbt_f + 18432;      // 73,728  (768x192 bf16)
    float* f2bt_f   = f1bt_f + 73728;        // 73,728  (192x768 bf16)

    __hip_bfloat16* xn    = (__hip_bfloat16*)xn_f;
    __hip_bfloat16* y1b   = (__hip_bfloat16*)bufC;                  // 65536x64
    __hip_bfloat16* qkvC  = (__hip_bfloat16*)bufC;                  // RATTx576
    __hip_bfloat16* attnC = (__hip_bfloat16*)(bufC + attnCoff);     // 6xRATTx32 planar
    __hip_bfloat16* h1    = (__hip_bfloat16*)bufC;                  // (merged: 65536, else 32768)x768
    __hip_bfloat16* rpbM   = (__hip_bfloat16*)rpbM_f;
    __hip_bfloat16* wb1    = (__hip_bfloat16*)wb1_f;
    __hip_bfloat16* wb2    = (__hip_bfloat16*)wb2_f;
    __hip_bfloat16* qkvbt  = (__hip_bfloat16*)qkvbt_f;
    __hip_bfloat16* projbt = (__hip_bfloat16*)projbt_f;
    __hip_bfloat16* f1bt   = (__hip_bfloat16*)f1bt_f;
    __hip_bfloat16* f2bt   = (__hip_bfloat16*)f2bt_f;

    // ---- fused prep (741,376 items) ----
    prep_all_k<<<(741376 + 255) / 256, 256, 0, stream>>>(rpi, rpbt, mask, rpbM, c1w, wb1, c2w, wb2,
                                                         qkvw, qkvbt, projw, projbt,
                                                         f1w, f1bt, f2w, f2bt);

    // ---- LN1 -> bf16 ----
    ln_k<<<NTOK / 4, 256, 0, stream>>>(x, n1g, n1b, xn);

    // ---- CAB conv branch (MFMA): y2 lives in d_out ----
    mconv_k<8, 192, 60, 64, 1, 1><<<dim3(512, 1), 256, 0, stream>>>(xn, 192, wb1, c1b, y1b);
    mconv_k<16, 64, 180, 180, 0, 0><<<dim3(256, 3), 256, 0, stream>>>(y1b, 64, wb2, c2b, out);
    chansum_k<<<256, 192, 0, stream>>>(out, partials);
    ca_k<<<1, 256, 0, stream>>>(partials, ca1w, ca1b, ca2w, ca2b, scalep);

    // ---- attention branch (merged: 1 chunk of 256 windows; fallback: 2x128) ----
    for (int ck = 0; ck < nck; ++ck) {
        const int rowoff = ck * RATT;
        mgemm_k<3, 128><<<dim3(RATT / 128, 5), 256, 0, stream>>>(
            (const unsigned short*)xn, (const unsigned short*)qkvbt, qkvb, nullptr, nullptr,
            qkvC, 192, 540, 576, rowoff);
        attn12_k<<<dim3(RATT / 256, 6), 256, 0, stream>>>(qkvC, rpbM, attnC, rowoff / 256, RATT);
        mgemm_k<5, 64><<<dim3(RATT / 128, 3), 256, 0, stream>>>(
            (const unsigned short*)attnC, (const unsigned short*)projbt, projb, x, scalep,
            out, 192, 180, RATT, rowoff);
    }

    // ---- LN2 (x2 in d_out) -> bf16 xm ----
    ln_k<<<NTOK / 4, 256, 0, stream>>>(out, n2g, n2b, xn);

    // ---- MLP (merged: single pass over all 65536 rows; h1 fits bufC exactly) ----
    const int nmlp = merged ? 1 : 2;
    const int RM = merged ? NTOK : RCHUNK;
    for (int ck = 0; ck < nmlp; ++ck) {
        const int rowoff = ck * RM;
        mgemm_k<1, 128><<<dim3(RM / 128, 6), 256, 0, stream>>>(
            (const unsigned short*)(xn + (size_t)rowoff * KP1), (const unsigned short*)f1bt,
            f1b, nullptr, nullptr, h1, 192, 720, 768, 0);
        mgemm_k<2, 64><<<dim3(RM / 128, 3), 256, 0, stream>>>(
            (const unsigned short*)h1, (const unsigned short*)f2bt, f2b,
            out + (size_t)rowoff * 180, nullptr, out + (size_t)rowoff * 180, 768, 180, 180, 0);
    }
}